// Round 11
// baseline (758.388 us; speedup 1.0000x reference)
//
#include <hip/hip_runtime.h>
#include <hip/hip_bf16.h>

#define EPSF 1e-20f

using short8  = __attribute__((ext_vector_type(8))) short;
using float4f = __attribute__((ext_vector_type(4))) float;

__device__ __forceinline__ unsigned short f2bf(float f) {
    __hip_bfloat16 h = __float2bfloat16(f);
    return __builtin_bit_cast(unsigned short, h);
}
__device__ __forceinline__ float bf2f(unsigned short u) {
    __hip_bfloat16 h = __builtin_bit_cast(__hip_bfloat16, u);
    return __bfloat162float(h);
}
__device__ __forceinline__ float frcp(float x) { return __builtin_amdgcn_rcpf(x); }

// ---------------------------------------------------------------------------
// Unified weight prep (one launch, 468 blocks):
//  blocks [0,420): linear idx
//    [0,800)      : conv1 weights -> wt1[tap*32+co] (fp32)
//    [992,107488) : MFMA A-fragments for w2..w6 (bf16, lane-exact order)
//      wf[((ks*2+cot)*64+lane)*8+j] = w[co][ci][tap],
//      co = cot*16+(lane&15); ci = (phase*32+(lane>>4)*8+j)^cxor; ks=phase*KK+tap
//  blocks [420,468): one WAVE per (layer,co) reciprocal weight sum
// ---------------------------------------------------------------------------
__global__ void wprep_k(const float* __restrict__ w1, const float* __restrict__ w2,
                        const float* __restrict__ w3, const float* __restrict__ w4,
                        const float* __restrict__ w5, const float* __restrict__ w6,
                        float* __restrict__ wt1,
                        float* __restrict__ is1, float* __restrict__ is2,
                        float* __restrict__ is3, float* __restrict__ is4,
                        float* __restrict__ is5, float* __restrict__ is6,
                        unsigned short* __restrict__ wf2, unsigned short* __restrict__ wf3,
                        unsigned short* __restrict__ wf4, unsigned short* __restrict__ wf5,
                        unsigned short* __restrict__ wf6) {
    const int tid = threadIdx.x;
    if (blockIdx.x >= 420) {
        // ---- wave-parallel reciprocal sums: 192 waves for 192 (task,co) ----
        int wid = (blockIdx.x - 420) * 4 + (tid >> 6);
        if (wid >= 192) return;
        int task = wid >> 5, co = wid & 31, lane = tid & 63;
        const float* w; int n; float* s;
        switch (task) {
            case 0: w = w1; n = 25;  s = is1; break;
            case 1: w = w2; n = 800; s = is2; break;
            case 2: w = w3; n = 800; s = is3; break;
            case 3: w = w4; n = 576; s = is4; break;
            case 4: w = w5; n = 576; s = is5; break;
            default: w = w6; n = 576; s = is6; break;
        }
        float acc = 0.f;
        for (int i = lane; i < n; i += 64) acc += w[co * n + i];
#pragma unroll
        for (int off = 1; off < 64; off <<= 1) acc += __shfl_xor(acc, off);
        if (lane == 0) s[co] = 1.0f / acc;
        return;
    }
    int idx = blockIdx.x * 256 + tid;
    if (idx < 800) {                       // conv1 transpose [tap][co]
        int co = idx / 25, t = idx % 25;
        wt1[t * 32 + co] = w1[idx];
        return;
    }
    if (idx < 992) return;                 // (sums handled by wave blocks)
    int r = idx - 992;
    const float* w; unsigned short* wf; int CIN, KK, cxor;
    if (r < 25600)        {             w = w2; wf = wf2; CIN = 32; KK = 25; cxor = 0;  }
    else if (r < 51200)   { r -= 25600; w = w3; wf = wf3; CIN = 32; KK = 25; cxor = 0;  }
    else if (r < 69632)   { r -= 51200; w = w4; wf = wf4; CIN = 64; KK = 9;  cxor = 0;  }
    else if (r < 88064)   { r -= 69632; w = w5; wf = wf5; CIN = 64; KK = 9;  cxor = 0;  }
    else if (r < 106496)  { r -= 88064; w = w6; wf = wf6; CIN = 64; KK = 9;  cxor = 32; }
    else return;
    int j = r & 7, lane = (r >> 3) & 63, cot = (r >> 9) & 1, ks = r >> 10;
    int phase = ks / KK, tap = ks - phase * KK;
    int co = cot * 16 + (lane & 15);
    int ci = (phase * 32 + (lane >> 4) * 8 + j) ^ cxor;
    wf[r] = f2bf(w[((long)co * CIN + ci) * KK + tap]);
}

// ---------------------------------------------------------------------------
// conv1: CIN=1 direct VALU conv, LDS-staged. Input planar fp32
// [b][{data,conf}][H][W]; output channel-last bf16 [b*2+pc][pix][32ci].
// ---------------------------------------------------------------------------
__global__ __launch_bounds__(256)
void conv1_k(const float* __restrict__ x, const float* __restrict__ wt,
             const float* __restrict__ bias, const float* __restrict__ is_,
             unsigned short* __restrict__ out, int H, int W) {
    constexpr int TIW = 36, TIH = 12, TSZ = TIW * TIH;  // 432
    __shared__ float sc[TSZ], sp[TSZ];
    const int tid = threadIdx.x;
    const int tx = tid & 31, ty = tid >> 5;
    const int ox0 = blockIdx.x * 32, oy0 = blockIdx.y * 8, b = blockIdx.z;
    const long HW = (long)H * W;
    const float* xd = x + (long)(b * 2) * HW;
    const float* xc = xd + HW;

    for (int i = tid; i < TSZ; i += 256) {
        int py = i / TIW, px = i - py * TIW;
        int gy = oy0 - 2 + py, gx = ox0 - 2 + px;
        float c = 0.f, d = 0.f;
        if (gy >= 0 && gy < H && gx >= 0 && gx < W) {
            long g = (long)gy * W + gx;
            c = xc[g]; d = xd[g];
        }
        sc[i] = c;
        sp[i] = d * c;
    }
    __syncthreads();

    float ac[32], ap[32];
#pragma unroll
    for (int i = 0; i < 32; ++i) { ac[i] = 0.f; ap[i] = 0.f; }
#pragma unroll
    for (int dy = 0; dy < 5; ++dy) {
#pragma unroll
        for (int dx = 0; dx < 5; ++dx) {
            const int li = (ty + dy) * TIW + tx + dx;
            float cf = sc[li];
            float pv = sp[li];
            const float* wr = wt + (dy * 5 + dx) * 32;
#pragma unroll
            for (int co = 0; co < 32; ++co) {
                ac[co] = fmaf(wr[co], cf, ac[co]);
                ap[co] = fmaf(wr[co], pv, ap[co]);
            }
        }
    }

    const int xx = ox0 + tx, yy = oy0 + ty;
    unsigned short* po = out + ((long)(b * 2 + 0) * HW + (long)yy * W + xx) * 32;
    unsigned short* co_ = out + ((long)(b * 2 + 1) * HW + (long)yy * W + xx) * 32;
#pragma unroll
    for (int g = 0; g < 4; ++g) {
        uint4 vp, vc;
        unsigned int pw[4], cw[4];
#pragma unroll
        for (int h = 0; h < 4; ++h) {
            int c0 = g * 8 + h * 2, c1 = c0 + 1;
            float d0 = ac[c0], d1 = ac[c1];
            float ox0v = fmaf(ap[c0], frcp(d0 + EPSF), bias[c0]);
            float ox1v = fmaf(ap[c1], frcp(d1 + EPSF), bias[c1]);
            float oc0 = d0 * is_[c0], oc1 = d1 * is_[c1];
            pw[h] = (unsigned int)f2bf(ox0v * oc0) | ((unsigned int)f2bf(ox1v * oc1) << 16);
            cw[h] = (unsigned int)f2bf(oc0) | ((unsigned int)f2bf(oc1) << 16);
        }
        vp.x = pw[0]; vp.y = pw[1]; vp.z = pw[2]; vp.w = pw[3];
        vc.x = cw[0]; vc.y = cw[1]; vc.z = cw[2]; vc.w = cw[3];
        *(uint4*)(po + g * 8) = vp;
        *(uint4*)(co_ + g * 8) = vc;
    }
}

// ---------------------------------------------------------------------------
// MFMA implicit-GEMM nconv (channel-last bf16 [b*2+pc][y][x][32ci]).
// R10 post-mortem: LDS pipe is the critical path (~45 of 66.8 us) and the
// 55.3 KB tile caps the kernel at 2 blocks/CU. This version uses a 16x16
// output tile: same 256 px/block and identical per-pixel MFMA/LDS work,
// but halo buffer 20x20 (KS=5) -> 51.2 KB -> 3 blocks/CU (24 waves/CU),
// and slightly lower halo fetch (1.56x vs 1.69x).
// 512 thr = 8 waves; wave wv owns rows {2wv, 2wv+1} (mt = row), 16 px each.
// Per tap: K=32 ci in one 16x16x32 k-step. D: col=lane&15=pixel,
// row=(lane>>4)*4+reg=co. NPH=2 stages src2 (half-res, up2'd in staging).
// LDS chunk-rotation swizzle kept; all slot indices compile-time
// (16,20 == 0 mod 4; TIW=18 case folds 2(mt+dy) into the table index, and
// 4wv == 0 mod 4). Epilogue bounces through LDS for full-line uint4 global
// writes (pix == n mod 4 still holds). FUSE7 fuses the final 1x1 nconv.
// ---------------------------------------------------------------------------
template <int KS, int NPH, bool FUSE7>
__global__ __launch_bounds__(512, 6)
void mconv_k(const unsigned short* __restrict__ s1,
             const unsigned short* __restrict__ s2,
             const unsigned short* __restrict__ wf,
             const float* __restrict__ bias, const float* __restrict__ sden,
             unsigned short* __restrict__ out, float* __restrict__ xout,
             const float* __restrict__ w7, const float* __restrict__ b7,
             int H, int W) {
    constexpr int R = KS / 2, KK = KS * KS;
    constexpr int TIH = 16 + KS - 1, TIW = 16 + KS - 1;   // 20 (KS=5) / 18 (KS=3)
    constexpr int RT = TIW & 3;                // 0 for KS=5, 2 for KS=3
    constexpr int PCS = TIH * TIW * 32;        // ushorts per pc-plane
    constexpr int NCH = TIH * TIW * 4;         // 16B chunks per pc-plane
    __shared__ unsigned short lds[2 * PCS];

    const int tid = threadIdx.x;
    const int wv = tid >> 6, lane = tid & 63, n = lane & 15, q = lane >> 4;
    const int ox0 = blockIdx.x * 16, oy0 = blockIdx.y * 16, b = blockIdx.z;
    const long HW = (long)H * W;

    float4f accP[2][2], accC[2][2];
#pragma unroll
    for (int mt = 0; mt < 2; ++mt)
#pragma unroll
        for (int ct = 0; ct < 2; ++ct) {
            accP[mt][ct] = (float4f)0.f;
            accC[mt][ct] = (float4f)0.f;
        }

    // per-lane swizzle-slot byte offsets: so4[j] = ((q + n + j)&3)*8
    // (pixel p = (2wv+mt+dy)*TIW + n + dx; p mod 4 = n+dx (+2(mt+dy) if RT=2))
    int so4[4];
#pragma unroll
    for (int j = 0; j < 4; ++j) so4[j] = ((q + n + j) & 3) * 8;
    const int PB = (2 * wv) * TIW + n;   // lane pixel base (2 rows per wave)

    for (int ph = 0; ph < NPH; ++ph) {
        const unsigned short* src = (NPH == 2 && ph == 1) ? s2 : s1;
        if (ph) __syncthreads();  // protect LDS from prior-phase readers
        // ---- stage tile (both pc planes) into LDS, zero-padded, swizzled ----
        for (int it = 0; it < (2 * NCH + 511) / 512; ++it) {
            int ch = it * 512 + tid;
            if (ch < 2 * NCH) {
                int pc = ch / NCH, c2 = ch - pc * NCH;
                int pix = c2 >> 2, k8 = c2 & 3;
                int py = pix / TIW, px = pix - py * TIW;
                int gy = oy0 - R + py, gx = ox0 - R + px;
                uint4 v = make_uint4(0, 0, 0, 0);
                if (gy >= 0 && gy < H && gx >= 0 && gx < W) {
                    long gi;
                    if (NPH == 2 && ph == 1)
                        gi = ((long)(b * 2 + pc) * (HW >> 2) +
                              (long)(gy >> 1) * (W >> 1) + (gx >> 1)) * 32 + k8 * 8;
                    else
                        gi = ((long)(b * 2 + pc) * HW + (long)gy * W + gx) * 32 + k8 * 8;
                    v = *(const uint4*)(src + gi);
                }
                *(uint4*)(lds + pc * PCS + pix * 32 + ((k8 + pix) & 3) * 8) = v;
            }
        }
        __syncthreads();
        // ---- tap loop: one mfma k-step per tap per (mt, cot, plane) ----
#pragma unroll
        for (int dy = 0; dy < KS; ++dy) {
#pragma unroll
            for (int dx = 0; dx < KS; ++dx) {
                const int ks = ph * KK + dy * KS + dx;
                short8 a0 = ((const short8*)wf)[(ks * 2 + 0) * 64 + lane];
                short8 a1 = ((const short8*)wf)[(ks * 2 + 1) * 64 + lane];
#pragma unroll
                for (int mt = 0; mt < 2; ++mt) {
                    const int p = PB + (mt + dy) * TIW + dx;
                    const int off = p * 32 + so4[(dx + RT * (mt + dy) / 2 * 2) & 3];
                    short8 bp = *(const short8*)(lds + off);
                    short8 bc = *(const short8*)(lds + off + PCS);
                    accP[mt][0] = __builtin_amdgcn_mfma_f32_16x16x32_bf16(a0, bp, accP[mt][0], 0, 0, 0);
                    accP[mt][1] = __builtin_amdgcn_mfma_f32_16x16x32_bf16(a1, bp, accP[mt][1], 0, 0, 0);
                    accC[mt][0] = __builtin_amdgcn_mfma_f32_16x16x32_bf16(a0, bc, accC[mt][0], 0, 0, 0);
                    accC[mt][1] = __builtin_amdgcn_mfma_f32_16x16x32_bf16(a1, bc, accC[mt][1], 0, 0, 0);
                }
            }
        }
    }

    // ---- epilogue ----
    float4f b4[2], s4[2];
    b4[0] = *(const float4f*)(bias + q * 4);
    b4[1] = *(const float4f*)(bias + 16 + q * 4);
    s4[0] = *(const float4f*)(sden + q * 4);
    s4[1] = *(const float4f*)(sden + 16 + q * 4);

    if (!FUSE7) {
        // LDS bounce (swizzled layout), one plane at a time: [pix(16x16)][32co]
        // bf16 (16 KB), then stream out lane-contiguous uint4.
#pragma unroll
        for (int pl = 0; pl < 2; ++pl) {
            __syncthreads();  // staging data no longer needed / prior copy done
#pragma unroll
            for (int mt = 0; mt < 2; ++mt) {
                const int pix = (2 * wv + mt) * 16 + n;
#pragma unroll
                for (int ct = 0; ct < 2; ++ct) {
                    unsigned int w0, w1;
                    if (pl == 0) {
                        float d0 = accC[mt][ct][0], d1 = accC[mt][ct][1];
                        float d2 = accC[mt][ct][2], d3 = accC[mt][ct][3];
                        float x0 = fmaf(accP[mt][ct][0], frcp(d0 + EPSF), b4[ct][0]) * (d0 * s4[ct][0]);
                        float x1 = fmaf(accP[mt][ct][1], frcp(d1 + EPSF), b4[ct][1]) * (d1 * s4[ct][1]);
                        float x2 = fmaf(accP[mt][ct][2], frcp(d2 + EPSF), b4[ct][2]) * (d2 * s4[ct][2]);
                        float x3 = fmaf(accP[mt][ct][3], frcp(d3 + EPSF), b4[ct][3]) * (d3 * s4[ct][3]);
                        w0 = (unsigned int)f2bf(x0) | ((unsigned int)f2bf(x1) << 16);
                        w1 = (unsigned int)f2bf(x2) | ((unsigned int)f2bf(x3) << 16);
                    } else {
                        float c0 = accC[mt][ct][0] * s4[ct][0], c1 = accC[mt][ct][1] * s4[ct][1];
                        float c2 = accC[mt][ct][2] * s4[ct][2], c3 = accC[mt][ct][3] * s4[ct][3];
                        w0 = (unsigned int)f2bf(c0) | ((unsigned int)f2bf(c1) << 16);
                        w1 = (unsigned int)f2bf(c2) | ((unsigned int)f2bf(c3) << 16);
                    }
                    uint2 v; v.x = w0; v.y = w1;
                    // chunk k = ct*2 + (q>>1); pix&3 == n&3
                    *(uint2*)(lds + pix * 32 + ((ct * 2 + (q >> 1) + n) & 3) * 8 + (q & 1) * 4) = v;
                }
            }
            __syncthreads();
            // 256 px * 64B = 16 KB -> 1024 uint4 -> 2 iterations of 512 thr
            const unsigned short* obase = out + (long)(b * 2 + pl) * HW * 32;
#pragma unroll
            for (int it = 0; it < 2; ++it) {
                int off = it * 512 + tid;          // 16B units
                int pix = off >> 2, sub = off & 3;
                uint4 v = *(const uint4*)(lds + pix * 32 + ((sub + pix) & 3) * 8);
                int ry = pix >> 4, rx = pix & 15;
                *(uint4*)(obase + ((long)(oy0 + ry) * W + ox0 + rx) * 32 + sub * 8) = v;
            }
        }
    } else {
        float4f w74[2];
        w74[0] = *(const float4f*)(w7 + q * 4);
        w74[1] = *(const float4f*)(w7 + 16 + q * 4);
        const float b7v = b7[0];
#pragma unroll
        for (int mt = 0; mt < 2; ++mt) {
            float num = 0.f, den = 0.f;
#pragma unroll
            for (int ct = 0; ct < 2; ++ct)
#pragma unroll
                for (int r = 0; r < 4; ++r) {
                    float d = accC[mt][ct][r];
                    float oxv = fmaf(accP[mt][ct][r], frcp(d + EPSF), b4[ct][r]);
                    float oc = d * s4[ct][r];
                    num = fmaf(w74[ct][r], oxv * oc, num);
                    den = fmaf(w74[ct][r], oc, den);
                }
            num += __shfl_xor(num, 16); num += __shfl_xor(num, 32);
            den += __shfl_xor(den, 16); den += __shfl_xor(den, 32);
            if (q == 0) {
                const int oy = oy0 + 2 * wv + mt;
                const int ox = ox0 + n;
                xout[(long)b * HW + (long)oy * W + ox] = fmaf(num, frcp(den + EPSF), b7v);
            }
        }
    }
}

// ---------------------------------------------------------------------------
// 2x2 stride-2 pool on channel-last layout: per (b, out-pixel, 8-ci chunk),
// per-ci argmax of c (first-max, row-major), gather p; both * 0.25.
// ---------------------------------------------------------------------------
__global__ void pool_k(const unsigned short* __restrict__ in, unsigned short* __restrict__ out,
                       int H2, int W2, int total) {
    int idx = blockIdx.x * 256 + threadIdx.x;
    if (idx >= total) return;
    int k8 = idx & 3, t = idx >> 2;
    long HW2 = (long)H2 * W2;
    int pix2 = (int)(t % HW2), b = (int)(t / HW2);
    int h = pix2 / W2, w = pix2 - h * W2;
    int W = W2 * 2;
    long HW = HW2 * 4;
    long p00 = ((long)(2 * h) * W + 2 * w) * 32 + k8 * 8;
    const unsigned short* pin = in + (long)(b * 2 + 0) * HW * 32;
    const unsigned short* cin = in + (long)(b * 2 + 1) * HW * 32;
    union U { uint4 v; unsigned short s[8]; };
    U c0, c1, c2, c3, p0, p1, p2, p3, rp, rc;
    c0.v = *(const uint4*)(cin + p00);             c1.v = *(const uint4*)(cin + p00 + 32);
    c2.v = *(const uint4*)(cin + p00 + (long)W * 32); c3.v = *(const uint4*)(cin + p00 + (long)W * 32 + 32);
    p0.v = *(const uint4*)(pin + p00);             p1.v = *(const uint4*)(pin + p00 + 32);
    p2.v = *(const uint4*)(pin + p00 + (long)W * 32); p3.v = *(const uint4*)(pin + p00 + (long)W * 32 + 32);
#pragma unroll
    for (int e = 0; e < 8; ++e) {
        float cv = bf2f(c0.s[e]), pv = bf2f(p0.s[e]);
        float c01 = bf2f(c1.s[e]); if (c01 > cv) { cv = c01; pv = bf2f(p1.s[e]); }
        float c10 = bf2f(c2.s[e]); if (c10 > cv) { cv = c10; pv = bf2f(p2.s[e]); }
        float c11 = bf2f(c3.s[e]); if (c11 > cv) { cv = c11; pv = bf2f(p3.s[e]); }
        rp.s[e] = f2bf(pv * 0.25f);
        rc.s[e] = f2bf(cv * 0.25f);
    }
    long ob = ((long)pix2) * 32 + k8 * 8;
    *(uint4*)(out + (long)(b * 2 + 0) * HW2 * 32 + ob) = rp.v;
    *(uint4*)(out + (long)(b * 2 + 1) * HW2 * 32 + ob) = rc.v;
}

// ---------------------------------------------------------------------------
extern "C" void kernel_launch(void* const* d_in, const int* in_sizes, int n_in,
                              void* d_out, int out_size, void* d_ws, size_t ws_size,
                              hipStream_t stream) {
    const float* x  = (const float*)d_in[0];
    const float* w1 = (const float*)d_in[1];
    const float* b1 = (const float*)d_in[2];
    const float* w2 = (const float*)d_in[3];
    const float* b2 = (const float*)d_in[4];
    const float* w3 = (const float*)d_in[5];
    const float* b3 = (const float*)d_in[6];
    const float* w4 = (const float*)d_in[7];
    const float* b4 = (const float*)d_in[8];
    const float* w5 = (const float*)d_in[9];
    const float* b5 = (const float*)d_in[10];
    const float* w6 = (const float*)d_in[11];
    const float* b6 = (const float*)d_in[12];
    const float* w7 = (const float*)d_in[13];
    const float* b7 = (const float*)d_in[14];

    const size_t HW1 = 512 * 512, HW2s = 256 * 256, HW3s = 128 * 128, HW4s = 64 * 64;

    // ---- weight arena (400000 B) ----
    const size_t WARENA = 400000;
    float* fa = (float*)d_ws;
    float *wt1 = fa;                 // 800 f
    float *s1 = wt1 + 800, *s2 = s1 + 32, *s3 = s2 + 32;   // reciprocal sums
    float *s4 = s3 + 32, *s5 = s4 + 32, *s6 = s5 + 32;     // ends at 992 f
    unsigned short* ua = (unsigned short*)((char*)d_ws + 4096);
    unsigned short *wf2 = ua;              // 25600
    unsigned short *wf3 = wf2 + 25600;     // 25600
    unsigned short *wf4 = wf3 + 25600;     // 18432
    unsigned short *wf5 = wf4 + 18432;     // 18432
    unsigned short *wf6 = wf5 + 18432;     // 18432 -> 213 KB < 400000-4096
    unsigned short* buf = (unsigned short*)((char*)d_ws + WARENA);

    // ---- stage buffers: channel-last bf16 [b*2+pc][HW][32] ----
    const size_t E1 = 2 * 2 * HW1 * 32;    // 33.55M ushort = 67.1 MB
    const size_t E2 = 2 * 2 * HW2s * 32, E3 = 2 * 2 * HW3s * 32, E4 = 2 * 2 * HW4s * 32;
    unsigned short* A = buf;
    unsigned short* B = A + E1;
    // lower-res alias inside B (sum = 22M ushorts <= E1)
    unsigned short* P = B;
    unsigned short* Q = P + E2;
    unsigned short* S = Q + E2;
    unsigned short* T = S + E3;
    unsigned short* U = T + E3;
    unsigned short* V = U + E4;

    if (ws_size < WARENA + 2 * E1 * sizeof(unsigned short)) return;  // 134.62 MB

    // ---- weight prep: single launch (frag blocks + 48 wave-sum blocks) ----
    wprep_k<<<468, 256, 0, stream>>>(w1, w2, w3, w4, w5, w6,
                                     wt1, s1, s2, s3, s4, s5, s6,
                                     wf2, wf3, wf4, wf5, wf6);

    dim3 blk(256), blkm(512);
    dim3 g1c(16, 64, 2);                               // conv1 (32x8 tiles)
    dim3 g1(32, 32, 2), g2(16, 16, 2), g3(8, 8, 2), g4(4, 4, 2);  // 16x16 tiles

    // ---- encoder ----
    conv1_k<<<g1c, blk, 0, stream>>>(x, wt1, b1, s1, A, 512, 512);
    mconv_k<5, 1, false><<<g1, blkm, 0, stream>>>(A, nullptr, wf2, b2, s2, B, nullptr, nullptr, nullptr, 512, 512);
    mconv_k<5, 1, false><<<g1, blkm, 0, stream>>>(B, nullptr, wf3, b3, s3, A, nullptr, nullptr, nullptr, 512, 512);  // x1 in A

    pool_k<<<(int)((2 * HW2s * 4 + 255) / 256), blk, 0, stream>>>(A, P, 256, 256, (int)(2 * HW2s * 4));
    mconv_k<5, 1, false><<<g2, blkm, 0, stream>>>(P, nullptr, wf2, b2, s2, Q, nullptr, nullptr, nullptr, 256, 256);
    mconv_k<5, 1, false><<<g2, blkm, 0, stream>>>(Q, nullptr, wf3, b3, s3, P, nullptr, nullptr, nullptr, 256, 256);  // x2 in P

    pool_k<<<(int)((2 * HW3s * 4 + 255) / 256), blk, 0, stream>>>(P, S, 128, 128, (int)(2 * HW3s * 4));
    mconv_k<5, 1, false><<<g3, blkm, 0, stream>>>(S, nullptr, wf2, b2, s2, T, nullptr, nullptr, nullptr, 128, 128);  // x3 in T

    pool_k<<<(int)((2 * HW4s * 4 + 255) / 256), blk, 0, stream>>>(T, U, 64, 64, (int)(2 * HW4s * 4));
    mconv_k<5, 1, false><<<g4, blkm, 0, stream>>>(U, nullptr, wf2, b2, s2, V, nullptr, nullptr, nullptr, 64, 64);    // x4 in V

    // ---- decoder ----
    mconv_k<3, 2, false><<<g3, blkm, 0, stream>>>(T, V, wf4, b4, s4, S, nullptr, nullptr, nullptr, 128, 128);        // x34 in S
    mconv_k<3, 2, false><<<g2, blkm, 0, stream>>>(P, S, wf5, b5, s5, Q, nullptr, nullptr, nullptr, 256, 256);        // x23 in Q
    mconv_k<3, 2, true><<<g1, blkm, 0, stream>>>(A, Q, wf6, b6, s6, nullptr, (float*)d_out, w7, b7, 512, 512);
}

// Round 12
// 405.861 us; speedup vs baseline: 1.8686x; 1.8686x over previous
//
#include <hip/hip_runtime.h>
#include <hip/hip_bf16.h>

#define EPSF 1e-20f

using short8  = __attribute__((ext_vector_type(8))) short;
using float4f = __attribute__((ext_vector_type(4))) float;

__device__ __forceinline__ unsigned short f2bf(float f) {
    __hip_bfloat16 h = __float2bfloat16(f);
    return __builtin_bit_cast(unsigned short, h);
}
__device__ __forceinline__ float bf2f(unsigned short u) {
    __hip_bfloat16 h = __builtin_bit_cast(__hip_bfloat16, u);
    return __bfloat162float(h);
}
__device__ __forceinline__ float frcp(float x) { return __builtin_amdgcn_rcpf(x); }

// ---------------------------------------------------------------------------
// Unified weight prep (one launch, 468 blocks):
//  blocks [0,420): linear idx
//    [0,800)      : conv1 weights -> wt1[tap*32+co] (fp32)
//    [992,107488) : MFMA A-fragments for w2..w6 (bf16, lane-exact order)
//      wf[((ks*2+cot)*64+lane)*8+j] = w[co][ci][tap],
//      co = cot*16+(lane&15); ci = (phase*32+(lane>>4)*8+j)^cxor; ks=phase*KK+tap
//  blocks [420,468): one WAVE per (layer,co) reciprocal weight sum
// ---------------------------------------------------------------------------
__global__ void wprep_k(const float* __restrict__ w1, const float* __restrict__ w2,
                        const float* __restrict__ w3, const float* __restrict__ w4,
                        const float* __restrict__ w5, const float* __restrict__ w6,
                        float* __restrict__ wt1,
                        float* __restrict__ is1, float* __restrict__ is2,
                        float* __restrict__ is3, float* __restrict__ is4,
                        float* __restrict__ is5, float* __restrict__ is6,
                        unsigned short* __restrict__ wf2, unsigned short* __restrict__ wf3,
                        unsigned short* __restrict__ wf4, unsigned short* __restrict__ wf5,
                        unsigned short* __restrict__ wf6) {
    const int tid = threadIdx.x;
    if (blockIdx.x >= 420) {
        // ---- wave-parallel reciprocal sums: 192 waves for 192 (task,co) ----
        int wid = (blockIdx.x - 420) * 4 + (tid >> 6);
        if (wid >= 192) return;
        int task = wid >> 5, co = wid & 31, lane = tid & 63;
        const float* w; int n; float* s;
        switch (task) {
            case 0: w = w1; n = 25;  s = is1; break;
            case 1: w = w2; n = 800; s = is2; break;
            case 2: w = w3; n = 800; s = is3; break;
            case 3: w = w4; n = 576; s = is4; break;
            case 4: w = w5; n = 576; s = is5; break;
            default: w = w6; n = 576; s = is6; break;
        }
        float acc = 0.f;
        for (int i = lane; i < n; i += 64) acc += w[co * n + i];
#pragma unroll
        for (int off = 1; off < 64; off <<= 1) acc += __shfl_xor(acc, off);
        if (lane == 0) s[co] = 1.0f / acc;
        return;
    }
    int idx = blockIdx.x * 256 + tid;
    if (idx < 800) {                       // conv1 transpose [tap][co]
        int co = idx / 25, t = idx % 25;
        wt1[t * 32 + co] = w1[idx];
        return;
    }
    if (idx < 992) return;                 // (sums handled by wave blocks)
    int r = idx - 992;
    const float* w; unsigned short* wf; int CIN, KK, cxor;
    if (r < 25600)        {             w = w2; wf = wf2; CIN = 32; KK = 25; cxor = 0;  }
    else if (r < 51200)   { r -= 25600; w = w3; wf = wf3; CIN = 32; KK = 25; cxor = 0;  }
    else if (r < 69632)   { r -= 51200; w = w4; wf = wf4; CIN = 64; KK = 9;  cxor = 0;  }
    else if (r < 88064)   { r -= 69632; w = w5; wf = wf5; CIN = 64; KK = 9;  cxor = 0;  }
    else if (r < 106496)  { r -= 88064; w = w6; wf = wf6; CIN = 64; KK = 9;  cxor = 32; }
    else return;
    int j = r & 7, lane = (r >> 3) & 63, cot = (r >> 9) & 1, ks = r >> 10;
    int phase = ks / KK, tap = ks - phase * KK;
    int co = cot * 16 + (lane & 15);
    int ci = (phase * 32 + (lane >> 4) * 8 + j) ^ cxor;
    wf[r] = f2bf(w[((long)co * CIN + ci) * KK + tap]);
}

// ---------------------------------------------------------------------------
// conv1: CIN=1 direct VALU conv, LDS-staged. Input planar fp32
// [b][{data,conf}][H][W]; output channel-last bf16 [b*2+pc][pix][32ci].
// ---------------------------------------------------------------------------
__global__ __launch_bounds__(256)
void conv1_k(const float* __restrict__ x, const float* __restrict__ wt,
             const float* __restrict__ bias, const float* __restrict__ is_,
             unsigned short* __restrict__ out, int H, int W) {
    constexpr int TIW = 36, TIH = 12, TSZ = TIW * TIH;  // 432
    __shared__ float sc[TSZ], sp[TSZ];
    const int tid = threadIdx.x;
    const int tx = tid & 31, ty = tid >> 5;
    const int ox0 = blockIdx.x * 32, oy0 = blockIdx.y * 8, b = blockIdx.z;
    const long HW = (long)H * W;
    const float* xd = x + (long)(b * 2) * HW;
    const float* xc = xd + HW;

    for (int i = tid; i < TSZ; i += 256) {
        int py = i / TIW, px = i - py * TIW;
        int gy = oy0 - 2 + py, gx = ox0 - 2 + px;
        float c = 0.f, d = 0.f;
        if (gy >= 0 && gy < H && gx >= 0 && gx < W) {
            long g = (long)gy * W + gx;
            c = xc[g]; d = xd[g];
        }
        sc[i] = c;
        sp[i] = d * c;
    }
    __syncthreads();

    float ac[32], ap[32];
#pragma unroll
    for (int i = 0; i < 32; ++i) { ac[i] = 0.f; ap[i] = 0.f; }
#pragma unroll
    for (int dy = 0; dy < 5; ++dy) {
#pragma unroll
        for (int dx = 0; dx < 5; ++dx) {
            const int li = (ty + dy) * TIW + tx + dx;
            float cf = sc[li];
            float pv = sp[li];
            const float* wr = wt + (dy * 5 + dx) * 32;
#pragma unroll
            for (int co = 0; co < 32; ++co) {
                ac[co] = fmaf(wr[co], cf, ac[co]);
                ap[co] = fmaf(wr[co], pv, ap[co]);
            }
        }
    }

    const int xx = ox0 + tx, yy = oy0 + ty;
    unsigned short* po = out + ((long)(b * 2 + 0) * HW + (long)yy * W + xx) * 32;
    unsigned short* co_ = out + ((long)(b * 2 + 1) * HW + (long)yy * W + xx) * 32;
#pragma unroll
    for (int g = 0; g < 4; ++g) {
        uint4 vp, vc;
        unsigned int pw[4], cw[4];
#pragma unroll
        for (int h = 0; h < 4; ++h) {
            int c0 = g * 8 + h * 2, c1 = c0 + 1;
            float d0 = ac[c0], d1 = ac[c1];
            float ox0v = fmaf(ap[c0], frcp(d0 + EPSF), bias[c0]);
            float ox1v = fmaf(ap[c1], frcp(d1 + EPSF), bias[c1]);
            float oc0 = d0 * is_[c0], oc1 = d1 * is_[c1];
            pw[h] = (unsigned int)f2bf(ox0v * oc0) | ((unsigned int)f2bf(ox1v * oc1) << 16);
            cw[h] = (unsigned int)f2bf(oc0) | ((unsigned int)f2bf(oc1) << 16);
        }
        vp.x = pw[0]; vp.y = pw[1]; vp.z = pw[2]; vp.w = pw[3];
        vc.x = cw[0]; vc.y = cw[1]; vc.z = cw[2]; vc.w = cw[3];
        *(uint4*)(po + g * 8) = vp;
        *(uint4*)(co_ + g * 8) = vc;
    }
}

// ---------------------------------------------------------------------------
// MFMA implicit-GEMM nconv (channel-last bf16 [b*2+pc][y][x][32ci]).
// 16x16 output tile (halo 20x20 @KS=5 -> 51.2 KB LDS -> 3 blocks/CU by LDS).
// R11 post-mortem: __launch_bounds__(512,6) forced VGPR=40 -> accumulator
// SPILL to scratch (WRITE_SIZE 495 MB, 758 us total). Bound relaxed to
// (512,4): kernel fits ~64 VGPR naturally (R10 evidence), LDS remains the
// occupancy limiter at 3 blocks/CU = 24 waves/CU.
// 512 thr = 8 waves; wave wv owns rows {2wv, 2wv+1} (mt = row), 16 px each.
// Per tap: K=32 ci in one 16x16x32 k-step. D: col=lane&15=pixel,
// row=(lane>>4)*4+reg=co. NPH=2 stages src2 (half-res, up2'd in staging).
// LDS chunk-rotation swizzle; slot indices compile-time. Epilogue bounces
// through LDS for full-line uint4 global writes. FUSE7 fuses the 1x1 nconv.
// ---------------------------------------------------------------------------
template <int KS, int NPH, bool FUSE7>
__global__ __launch_bounds__(512, 4)
void mconv_k(const unsigned short* __restrict__ s1,
             const unsigned short* __restrict__ s2,
             const unsigned short* __restrict__ wf,
             const float* __restrict__ bias, const float* __restrict__ sden,
             unsigned short* __restrict__ out, float* __restrict__ xout,
             const float* __restrict__ w7, const float* __restrict__ b7,
             int H, int W) {
    constexpr int R = KS / 2, KK = KS * KS;
    constexpr int TIH = 16 + KS - 1, TIW = 16 + KS - 1;   // 20 (KS=5) / 18 (KS=3)
    constexpr int RT = TIW & 3;                // 0 for KS=5, 2 for KS=3
    constexpr int PCS = TIH * TIW * 32;        // ushorts per pc-plane
    constexpr int NCH = TIH * TIW * 4;         // 16B chunks per pc-plane
    __shared__ unsigned short lds[2 * PCS];

    const int tid = threadIdx.x;
    const int wv = tid >> 6, lane = tid & 63, n = lane & 15, q = lane >> 4;
    const int ox0 = blockIdx.x * 16, oy0 = blockIdx.y * 16, b = blockIdx.z;
    const long HW = (long)H * W;

    float4f accP[2][2], accC[2][2];
#pragma unroll
    for (int mt = 0; mt < 2; ++mt)
#pragma unroll
        for (int ct = 0; ct < 2; ++ct) {
            accP[mt][ct] = (float4f)0.f;
            accC[mt][ct] = (float4f)0.f;
        }

    // per-lane swizzle-slot byte offsets: so4[j] = ((q + n + j)&3)*8
    // (pixel p = (2wv+mt+dy)*TIW + n + dx; p mod 4 = n+dx (+2(mt+dy) if RT=2))
    int so4[4];
#pragma unroll
    for (int j = 0; j < 4; ++j) so4[j] = ((q + n + j) & 3) * 8;
    const int PB = (2 * wv) * TIW + n;   // lane pixel base (2 rows per wave)

    for (int ph = 0; ph < NPH; ++ph) {
        const unsigned short* src = (NPH == 2 && ph == 1) ? s2 : s1;
        if (ph) __syncthreads();  // protect LDS from prior-phase readers
        // ---- stage tile (both pc planes) into LDS, zero-padded, swizzled ----
        for (int it = 0; it < (2 * NCH + 511) / 512; ++it) {
            int ch = it * 512 + tid;
            if (ch < 2 * NCH) {
                int pc = ch / NCH, c2 = ch - pc * NCH;
                int pix = c2 >> 2, k8 = c2 & 3;
                int py = pix / TIW, px = pix - py * TIW;
                int gy = oy0 - R + py, gx = ox0 - R + px;
                uint4 v = make_uint4(0, 0, 0, 0);
                if (gy >= 0 && gy < H && gx >= 0 && gx < W) {
                    long gi;
                    if (NPH == 2 && ph == 1)
                        gi = ((long)(b * 2 + pc) * (HW >> 2) +
                              (long)(gy >> 1) * (W >> 1) + (gx >> 1)) * 32 + k8 * 8;
                    else
                        gi = ((long)(b * 2 + pc) * HW + (long)gy * W + gx) * 32 + k8 * 8;
                    v = *(const uint4*)(src + gi);
                }
                *(uint4*)(lds + pc * PCS + pix * 32 + ((k8 + pix) & 3) * 8) = v;
            }
        }
        __syncthreads();
        // ---- tap loop: one mfma k-step per tap per (mt, cot, plane) ----
#pragma unroll
        for (int dy = 0; dy < KS; ++dy) {
#pragma unroll
            for (int dx = 0; dx < KS; ++dx) {
                const int ks = ph * KK + dy * KS + dx;
                short8 a0 = ((const short8*)wf)[(ks * 2 + 0) * 64 + lane];
                short8 a1 = ((const short8*)wf)[(ks * 2 + 1) * 64 + lane];
#pragma unroll
                for (int mt = 0; mt < 2; ++mt) {
                    const int p = PB + (mt + dy) * TIW + dx;
                    const int off = p * 32 + so4[(dx + RT * (mt + dy) / 2 * 2) & 3];
                    short8 bp = *(const short8*)(lds + off);
                    short8 bc = *(const short8*)(lds + off + PCS);
                    accP[mt][0] = __builtin_amdgcn_mfma_f32_16x16x32_bf16(a0, bp, accP[mt][0], 0, 0, 0);
                    accP[mt][1] = __builtin_amdgcn_mfma_f32_16x16x32_bf16(a1, bp, accP[mt][1], 0, 0, 0);
                    accC[mt][0] = __builtin_amdgcn_mfma_f32_16x16x32_bf16(a0, bc, accC[mt][0], 0, 0, 0);
                    accC[mt][1] = __builtin_amdgcn_mfma_f32_16x16x32_bf16(a1, bc, accC[mt][1], 0, 0, 0);
                }
            }
        }
    }

    // ---- epilogue ----
    float4f b4[2], s4[2];
    b4[0] = *(const float4f*)(bias + q * 4);
    b4[1] = *(const float4f*)(bias + 16 + q * 4);
    s4[0] = *(const float4f*)(sden + q * 4);
    s4[1] = *(const float4f*)(sden + 16 + q * 4);

    if (!FUSE7) {
        // LDS bounce (swizzled layout), one plane at a time: [pix(16x16)][32co]
        // bf16 (16 KB), then stream out lane-contiguous uint4.
#pragma unroll
        for (int pl = 0; pl < 2; ++pl) {
            __syncthreads();  // staging data no longer needed / prior copy done
#pragma unroll
            for (int mt = 0; mt < 2; ++mt) {
                const int pix = (2 * wv + mt) * 16 + n;
#pragma unroll
                for (int ct = 0; ct < 2; ++ct) {
                    unsigned int w0, w1;
                    if (pl == 0) {
                        float d0 = accC[mt][ct][0], d1 = accC[mt][ct][1];
                        float d2 = accC[mt][ct][2], d3 = accC[mt][ct][3];
                        float x0 = fmaf(accP[mt][ct][0], frcp(d0 + EPSF), b4[ct][0]) * (d0 * s4[ct][0]);
                        float x1 = fmaf(accP[mt][ct][1], frcp(d1 + EPSF), b4[ct][1]) * (d1 * s4[ct][1]);
                        float x2 = fmaf(accP[mt][ct][2], frcp(d2 + EPSF), b4[ct][2]) * (d2 * s4[ct][2]);
                        float x3 = fmaf(accP[mt][ct][3], frcp(d3 + EPSF), b4[ct][3]) * (d3 * s4[ct][3]);
                        w0 = (unsigned int)f2bf(x0) | ((unsigned int)f2bf(x1) << 16);
                        w1 = (unsigned int)f2bf(x2) | ((unsigned int)f2bf(x3) << 16);
                    } else {
                        float c0 = accC[mt][ct][0] * s4[ct][0], c1 = accC[mt][ct][1] * s4[ct][1];
                        float c2 = accC[mt][ct][2] * s4[ct][2], c3 = accC[mt][ct][3] * s4[ct][3];
                        w0 = (unsigned int)f2bf(c0) | ((unsigned int)f2bf(c1) << 16);
                        w1 = (unsigned int)f2bf(c2) | ((unsigned int)f2bf(c3) << 16);
                    }
                    uint2 v; v.x = w0; v.y = w1;
                    // chunk k = ct*2 + (q>>1); pix&3 == n&3
                    *(uint2*)(lds + pix * 32 + ((ct * 2 + (q >> 1) + n) & 3) * 8 + (q & 1) * 4) = v;
                }
            }
            __syncthreads();
            // 256 px * 64B = 16 KB -> 1024 uint4 -> 2 iterations of 512 thr
            const unsigned short* obase = out + (long)(b * 2 + pl) * HW * 32;
#pragma unroll
            for (int it = 0; it < 2; ++it) {
                int off = it * 512 + tid;          // 16B units
                int pix = off >> 2, sub = off & 3;
                uint4 v = *(const uint4*)(lds + pix * 32 + ((sub + pix) & 3) * 8);
                int ry = pix >> 4, rx = pix & 15;
                *(uint4*)(obase + ((long)(oy0 + ry) * W + ox0 + rx) * 32 + sub * 8) = v;
            }
        }
    } else {
        float4f w74[2];
        w74[0] = *(const float4f*)(w7 + q * 4);
        w74[1] = *(const float4f*)(w7 + 16 + q * 4);
        const float b7v = b7[0];
#pragma unroll
        for (int mt = 0; mt < 2; ++mt) {
            float num = 0.f, den = 0.f;
#pragma unroll
            for (int ct = 0; ct < 2; ++ct)
#pragma unroll
                for (int r = 0; r < 4; ++r) {
                    float d = accC[mt][ct][r];
                    float oxv = fmaf(accP[mt][ct][r], frcp(d + EPSF), b4[ct][r]);
                    float oc = d * s4[ct][r];
                    num = fmaf(w74[ct][r], oxv * oc, num);
                    den = fmaf(w74[ct][r], oc, den);
                }
            num += __shfl_xor(num, 16); num += __shfl_xor(num, 32);
            den += __shfl_xor(den, 16); den += __shfl_xor(den, 32);
            if (q == 0) {
                const int oy = oy0 + 2 * wv + mt;
                const int ox = ox0 + n;
                xout[(long)b * HW + (long)oy * W + ox] = fmaf(num, frcp(den + EPSF), b7v);
            }
        }
    }
}

// ---------------------------------------------------------------------------
// 2x2 stride-2 pool on channel-last layout: per (b, out-pixel, 8-ci chunk),
// per-ci argmax of c (first-max, row-major), gather p; both * 0.25.
// ---------------------------------------------------------------------------
__global__ void pool_k(const unsigned short* __restrict__ in, unsigned short* __restrict__ out,
                       int H2, int W2, int total) {
    int idx = blockIdx.x * 256 + threadIdx.x;
    if (idx >= total) return;
    int k8 = idx & 3, t = idx >> 2;
    long HW2 = (long)H2 * W2;
    int pix2 = (int)(t % HW2), b = (int)(t / HW2);
    int h = pix2 / W2, w = pix2 - h * W2;
    int W = W2 * 2;
    long HW = HW2 * 4;
    long p00 = ((long)(2 * h) * W + 2 * w) * 32 + k8 * 8;
    const unsigned short* pin = in + (long)(b * 2 + 0) * HW * 32;
    const unsigned short* cin = in + (long)(b * 2 + 1) * HW * 32;
    union U { uint4 v; unsigned short s[8]; };
    U c0, c1, c2, c3, p0, p1, p2, p3, rp, rc;
    c0.v = *(const uint4*)(cin + p00);             c1.v = *(const uint4*)(cin + p00 + 32);
    c2.v = *(const uint4*)(cin + p00 + (long)W * 32); c3.v = *(const uint4*)(cin + p00 + (long)W * 32 + 32);
    p0.v = *(const uint4*)(pin + p00);             p1.v = *(const uint4*)(pin + p00 + 32);
    p2.v = *(const uint4*)(pin + p00 + (long)W * 32); p3.v = *(const uint4*)(pin + p00 + (long)W * 32 + 32);
#pragma unroll
    for (int e = 0; e < 8; ++e) {
        float cv = bf2f(c0.s[e]), pv = bf2f(p0.s[e]);
        float c01 = bf2f(c1.s[e]); if (c01 > cv) { cv = c01; pv = bf2f(p1.s[e]); }
        float c10 = bf2f(c2.s[e]); if (c10 > cv) { cv = c10; pv = bf2f(p2.s[e]); }
        float c11 = bf2f(c3.s[e]); if (c11 > cv) { cv = c11; pv = bf2f(p3.s[e]); }
        rp.s[e] = f2bf(pv * 0.25f);
        rc.s[e] = f2bf(cv * 0.25f);
    }
    long ob = ((long)pix2) * 32 + k8 * 8;
    *(uint4*)(out + (long)(b * 2 + 0) * HW2 * 32 + ob) = rp.v;
    *(uint4*)(out + (long)(b * 2 + 1) * HW2 * 32 + ob) = rc.v;
}

// ---------------------------------------------------------------------------
extern "C" void kernel_launch(void* const* d_in, const int* in_sizes, int n_in,
                              void* d_out, int out_size, void* d_ws, size_t ws_size,
                              hipStream_t stream) {
    const float* x  = (const float*)d_in[0];
    const float* w1 = (const float*)d_in[1];
    const float* b1 = (const float*)d_in[2];
    const float* w2 = (const float*)d_in[3];
    const float* b2 = (const float*)d_in[4];
    const float* w3 = (const float*)d_in[5];
    const float* b3 = (const float*)d_in[6];
    const float* w4 = (const float*)d_in[7];
    const float* b4 = (const float*)d_in[8];
    const float* w5 = (const float*)d_in[9];
    const float* b5 = (const float*)d_in[10];
    const float* w6 = (const float*)d_in[11];
    const float* b6 = (const float*)d_in[12];
    const float* w7 = (const float*)d_in[13];
    const float* b7 = (const float*)d_in[14];

    const size_t HW1 = 512 * 512, HW2s = 256 * 256, HW3s = 128 * 128, HW4s = 64 * 64;

    // ---- weight arena (400000 B) ----
    const size_t WARENA = 400000;
    float* fa = (float*)d_ws;
    float *wt1 = fa;                 // 800 f
    float *s1 = wt1 + 800, *s2 = s1 + 32, *s3 = s2 + 32;   // reciprocal sums
    float *s4 = s3 + 32, *s5 = s4 + 32, *s6 = s5 + 32;     // ends at 992 f
    unsigned short* ua = (unsigned short*)((char*)d_ws + 4096);
    unsigned short *wf2 = ua;              // 25600
    unsigned short *wf3 = wf2 + 25600;     // 25600
    unsigned short *wf4 = wf3 + 25600;     // 18432
    unsigned short *wf5 = wf4 + 18432;     // 18432
    unsigned short *wf6 = wf5 + 18432;     // 18432 -> 213 KB < 400000-4096
    unsigned short* buf = (unsigned short*)((char*)d_ws + WARENA);

    // ---- stage buffers: channel-last bf16 [b*2+pc][HW][32] ----
    const size_t E1 = 2 * 2 * HW1 * 32;    // 33.55M ushort = 67.1 MB
    const size_t E2 = 2 * 2 * HW2s * 32, E3 = 2 * 2 * HW3s * 32, E4 = 2 * 2 * HW4s * 32;
    unsigned short* A = buf;
    unsigned short* B = A + E1;
    // lower-res alias inside B (sum = 22M ushorts <= E1)
    unsigned short* P = B;
    unsigned short* Q = P + E2;
    unsigned short* S = Q + E2;
    unsigned short* T = S + E3;
    unsigned short* U = T + E3;
    unsigned short* V = U + E4;

    if (ws_size < WARENA + 2 * E1 * sizeof(unsigned short)) return;  // 134.62 MB

    // ---- weight prep: single launch (frag blocks + 48 wave-sum blocks) ----
    wprep_k<<<468, 256, 0, stream>>>(w1, w2, w3, w4, w5, w6,
                                     wt1, s1, s2, s3, s4, s5, s6,
                                     wf2, wf3, wf4, wf5, wf6);

    dim3 blk(256), blkm(512);
    dim3 g1c(16, 64, 2);                               // conv1 (32x8 tiles)
    dim3 g1(32, 32, 2), g2(16, 16, 2), g3(8, 8, 2), g4(4, 4, 2);  // 16x16 tiles

    // ---- encoder ----
    conv1_k<<<g1c, blk, 0, stream>>>(x, wt1, b1, s1, A, 512, 512);
    mconv_k<5, 1, false><<<g1, blkm, 0, stream>>>(A, nullptr, wf2, b2, s2, B, nullptr, nullptr, nullptr, 512, 512);
    mconv_k<5, 1, false><<<g1, blkm, 0, stream>>>(B, nullptr, wf3, b3, s3, A, nullptr, nullptr, nullptr, 512, 512);  // x1 in A

    pool_k<<<(int)((2 * HW2s * 4 + 255) / 256), blk, 0, stream>>>(A, P, 256, 256, (int)(2 * HW2s * 4));
    mconv_k<5, 1, false><<<g2, blkm, 0, stream>>>(P, nullptr, wf2, b2, s2, Q, nullptr, nullptr, nullptr, 256, 256);
    mconv_k<5, 1, false><<<g2, blkm, 0, stream>>>(Q, nullptr, wf3, b3, s3, P, nullptr, nullptr, nullptr, 256, 256);  // x2 in P

    pool_k<<<(int)((2 * HW3s * 4 + 255) / 256), blk, 0, stream>>>(P, S, 128, 128, (int)(2 * HW3s * 4));
    mconv_k<5, 1, false><<<g3, blkm, 0, stream>>>(S, nullptr, wf2, b2, s2, T, nullptr, nullptr, nullptr, 128, 128);  // x3 in T

    pool_k<<<(int)((2 * HW4s * 4 + 255) / 256), blk, 0, stream>>>(T, U, 64, 64, (int)(2 * HW4s * 4));
    mconv_k<5, 1, false><<<g4, blkm, 0, stream>>>(U, nullptr, wf2, b2, s2, V, nullptr, nullptr, nullptr, 64, 64);    // x4 in V

    // ---- decoder ----
    mconv_k<3, 2, false><<<g3, blkm, 0, stream>>>(T, V, wf4, b4, s4, S, nullptr, nullptr, nullptr, 128, 128);        // x34 in S
    mconv_k<3, 2, false><<<g2, blkm, 0, stream>>>(P, S, wf5, b5, s5, Q, nullptr, nullptr, nullptr, 256, 256);        // x23 in Q
    mconv_k<3, 2, true><<<g1, blkm, 0, stream>>>(A, Q, wf6, b6, s6, nullptr, (float*)d_out, w7, b7, 512, 512);
}

// Round 13
// 392.859 us; speedup vs baseline: 1.9304x; 1.0331x over previous
//
#include <hip/hip_runtime.h>
#include <hip/hip_bf16.h>

#define EPSF 1e-20f

using short8  = __attribute__((ext_vector_type(8))) short;
using float4f = __attribute__((ext_vector_type(4))) float;

__device__ __forceinline__ unsigned short f2bf(float f) {
    __hip_bfloat16 h = __float2bfloat16(f);
    return __builtin_bit_cast(unsigned short, h);
}
__device__ __forceinline__ float bf2f(unsigned short u) {
    __hip_bfloat16 h = __builtin_bit_cast(__hip_bfloat16, u);
    return __bfloat162float(h);
}
__device__ __forceinline__ float frcp(float x) { return __builtin_amdgcn_rcpf(x); }

// ---------------------------------------------------------------------------
// Unified weight prep (one launch, 468 blocks):
//  blocks [0,420): linear idx
//    [0,800)      : conv1 weights -> wt1[tap*32+co] (fp32)
//    [992,107488) : MFMA A-fragments for w2..w6 (bf16, lane-exact order)
//  blocks [420,468): one WAVE per (layer,co) reciprocal weight sum
// ---------------------------------------------------------------------------
__global__ void wprep_k(const float* __restrict__ w1, const float* __restrict__ w2,
                        const float* __restrict__ w3, const float* __restrict__ w4,
                        const float* __restrict__ w5, const float* __restrict__ w6,
                        float* __restrict__ wt1,
                        float* __restrict__ is1, float* __restrict__ is2,
                        float* __restrict__ is3, float* __restrict__ is4,
                        float* __restrict__ is5, float* __restrict__ is6,
                        unsigned short* __restrict__ wf2, unsigned short* __restrict__ wf3,
                        unsigned short* __restrict__ wf4, unsigned short* __restrict__ wf5,
                        unsigned short* __restrict__ wf6) {
    const int tid = threadIdx.x;
    if (blockIdx.x >= 420) {
        int wid = (blockIdx.x - 420) * 4 + (tid >> 6);
        if (wid >= 192) return;
        int task = wid >> 5, co = wid & 31, lane = tid & 63;
        const float* w; int n; float* s;
        switch (task) {
            case 0: w = w1; n = 25;  s = is1; break;
            case 1: w = w2; n = 800; s = is2; break;
            case 2: w = w3; n = 800; s = is3; break;
            case 3: w = w4; n = 576; s = is4; break;
            case 4: w = w5; n = 576; s = is5; break;
            default: w = w6; n = 576; s = is6; break;
        }
        float acc = 0.f;
        for (int i = lane; i < n; i += 64) acc += w[co * n + i];
#pragma unroll
        for (int off = 1; off < 64; off <<= 1) acc += __shfl_xor(acc, off);
        if (lane == 0) s[co] = 1.0f / acc;
        return;
    }
    int idx = blockIdx.x * 256 + tid;
    if (idx < 800) {
        int co = idx / 25, t = idx % 25;
        wt1[t * 32 + co] = w1[idx];
        return;
    }
    if (idx < 992) return;
    int r = idx - 992;
    const float* w; unsigned short* wf; int CIN, KK, cxor;
    if (r < 25600)        {             w = w2; wf = wf2; CIN = 32; KK = 25; cxor = 0;  }
    else if (r < 51200)   { r -= 25600; w = w3; wf = wf3; CIN = 32; KK = 25; cxor = 0;  }
    else if (r < 69632)   { r -= 51200; w = w4; wf = wf4; CIN = 64; KK = 9;  cxor = 0;  }
    else if (r < 88064)   { r -= 69632; w = w5; wf = wf5; CIN = 64; KK = 9;  cxor = 0;  }
    else if (r < 106496)  { r -= 88064; w = w6; wf = wf6; CIN = 64; KK = 9;  cxor = 32; }
    else return;
    int j = r & 7, lane = (r >> 3) & 63, cot = (r >> 9) & 1, ks = r >> 10;
    int phase = ks / KK, tap = ks - phase * KK;
    int co = cot * 16 + (lane & 15);
    int ci = (phase * 32 + (lane >> 4) * 8 + j) ^ cxor;
    wf[r] = f2bf(w[((long)co * CIN + ci) * KK + tap]);
}

// ---------------------------------------------------------------------------
// conv1: CIN=1 direct VALU conv, LDS-staged. Input planar fp32
// [b][{data,conf}][H][W]; output channel-last bf16 [b*2+pc][pix][32ci].
// ---------------------------------------------------------------------------
__global__ __launch_bounds__(256)
void conv1_k(const float* __restrict__ x, const float* __restrict__ wt,
             const float* __restrict__ bias, const float* __restrict__ is_,
             unsigned short* __restrict__ out, int H, int W) {
    constexpr int TIW = 36, TIH = 12, TSZ = TIW * TIH;  // 432
    __shared__ float sc[TSZ], sp[TSZ];
    const int tid = threadIdx.x;
    const int tx = tid & 31, ty = tid >> 5;
    const int ox0 = blockIdx.x * 32, oy0 = blockIdx.y * 8, b = blockIdx.z;
    const long HW = (long)H * W;
    const float* xd = x + (long)(b * 2) * HW;
    const float* xc = xd + HW;

    for (int i = tid; i < TSZ; i += 256) {
        int py = i / TIW, px = i - py * TIW;
        int gy = oy0 - 2 + py, gx = ox0 - 2 + px;
        float c = 0.f, d = 0.f;
        if (gy >= 0 && gy < H && gx >= 0 && gx < W) {
            long g = (long)gy * W + gx;
            c = xc[g]; d = xd[g];
        }
        sc[i] = c;
        sp[i] = d * c;
    }
    __syncthreads();

    float ac[32], ap[32];
#pragma unroll
    for (int i = 0; i < 32; ++i) { ac[i] = 0.f; ap[i] = 0.f; }
#pragma unroll
    for (int dy = 0; dy < 5; ++dy) {
#pragma unroll
        for (int dx = 0; dx < 5; ++dx) {
            const int li = (ty + dy) * TIW + tx + dx;
            float cf = sc[li];
            float pv = sp[li];
            const float* wr = wt + (dy * 5 + dx) * 32;
#pragma unroll
            for (int co = 0; co < 32; ++co) {
                ac[co] = fmaf(wr[co], cf, ac[co]);
                ap[co] = fmaf(wr[co], pv, ap[co]);
            }
        }
    }

    const int xx = ox0 + tx, yy = oy0 + ty;
    unsigned short* po = out + ((long)(b * 2 + 0) * HW + (long)yy * W + xx) * 32;
    unsigned short* co_ = out + ((long)(b * 2 + 1) * HW + (long)yy * W + xx) * 32;
#pragma unroll
    for (int g = 0; g < 4; ++g) {
        uint4 vp, vc;
        unsigned int pw[4], cw[4];
#pragma unroll
        for (int h = 0; h < 4; ++h) {
            int c0 = g * 8 + h * 2, c1 = c0 + 1;
            float d0 = ac[c0], d1 = ac[c1];
            float ox0v = fmaf(ap[c0], frcp(d0 + EPSF), bias[c0]);
            float ox1v = fmaf(ap[c1], frcp(d1 + EPSF), bias[c1]);
            float oc0 = d0 * is_[c0], oc1 = d1 * is_[c1];
            pw[h] = (unsigned int)f2bf(ox0v * oc0) | ((unsigned int)f2bf(ox1v * oc1) << 16);
            cw[h] = (unsigned int)f2bf(oc0) | ((unsigned int)f2bf(oc1) << 16);
        }
        vp.x = pw[0]; vp.y = pw[1]; vp.z = pw[2]; vp.w = pw[3];
        vc.x = cw[0]; vc.y = cw[1]; vc.z = cw[2]; vc.w = cw[3];
        *(uint4*)(po + g * 8) = vp;
        *(uint4*)(co_ + g * 8) = vc;
    }
}

// ---------------------------------------------------------------------------
// MFMA implicit-GEMM nconv (channel-last bf16 [b*2+pc][y][x][32ci]).
// 16x16 output tile, 512 thr = 8 waves; wave wv owns rows {2wv,2wv+1}
// (mt = row), 16 px each. Per tap: K=32 ci in one 16x16x32 k-step.
// D: col=lane&15=pixel, row=(lane>>4)*4+reg=co. NPH=2 stages src2.
// R12 post-mortem: LDS-contention-bound; R13 fixes the epilogue-bounce
// 4-way bank conflict (slot rotation now includes n>>2 / pix>>2 — lanes
// n, n+4, n+8, n+12 previously shared a bank pair; SQ_LDS_BANK_CONFLICT
// 6.16M was constant across rounds = structural epilogue component).
// POOL: fuse the 2x2 stride-2 max-pool (argmax on c, first-max row-major)
// into the epilogue: rows mt=0/1 in-lane, columns via __shfl_xor(.,1)
// (DPP quad-perm); even-n lanes write the pooled 8x8 tile.
// FUSE7 fuses the final 1x1 nconv.
// ---------------------------------------------------------------------------
template <int KS, int NPH, bool FUSE7, bool POOL>
__global__ __launch_bounds__(512, 4)
void mconv_k(const unsigned short* __restrict__ s1,
             const unsigned short* __restrict__ s2,
             const unsigned short* __restrict__ wf,
             const float* __restrict__ bias, const float* __restrict__ sden,
             unsigned short* __restrict__ out, float* __restrict__ xout,
             const float* __restrict__ w7, const float* __restrict__ b7,
             unsigned short* __restrict__ pout,
             int H, int W) {
    constexpr int R = KS / 2, KK = KS * KS;
    constexpr int TIH = 16 + KS - 1, TIW = 16 + KS - 1;   // 20 (KS=5) / 18 (KS=3)
    constexpr int RT = TIW & 3;                // 0 for KS=5, 2 for KS=3
    constexpr int PCS = TIH * TIW * 32;        // ushorts per pc-plane
    constexpr int NCH = TIH * TIW * 4;         // 16B chunks per pc-plane
    __shared__ unsigned short lds[2 * PCS];

    const int tid = threadIdx.x;
    const int wv = tid >> 6, lane = tid & 63, n = lane & 15, q = lane >> 4;
    const int ox0 = blockIdx.x * 16, oy0 = blockIdx.y * 16, b = blockIdx.z;
    const long HW = (long)H * W;

    float4f accP[2][2], accC[2][2];
#pragma unroll
    for (int mt = 0; mt < 2; ++mt)
#pragma unroll
        for (int ct = 0; ct < 2; ++ct) {
            accP[mt][ct] = (float4f)0.f;
            accC[mt][ct] = (float4f)0.f;
        }

    // per-lane swizzle-slot byte offsets: so4[j] = ((q + n + j)&3)*8
    int so4[4];
#pragma unroll
    for (int j = 0; j < 4; ++j) so4[j] = ((q + n + j) & 3) * 8;
    const int PB = (2 * wv) * TIW + n;   // lane pixel base (2 rows per wave)

    for (int ph = 0; ph < NPH; ++ph) {
        const unsigned short* src = (NPH == 2 && ph == 1) ? s2 : s1;
        if (ph) __syncthreads();
        // ---- stage tile (both pc planes) into LDS, zero-padded, swizzled ----
        for (int it = 0; it < (2 * NCH + 511) / 512; ++it) {
            int ch = it * 512 + tid;
            if (ch < 2 * NCH) {
                int pc = ch / NCH, c2 = ch - pc * NCH;
                int pix = c2 >> 2, k8 = c2 & 3;
                int py = pix / TIW, px = pix - py * TIW;
                int gy = oy0 - R + py, gx = ox0 - R + px;
                uint4 v = make_uint4(0, 0, 0, 0);
                if (gy >= 0 && gy < H && gx >= 0 && gx < W) {
                    long gi;
                    if (NPH == 2 && ph == 1)
                        gi = ((long)(b * 2 + pc) * (HW >> 2) +
                              (long)(gy >> 1) * (W >> 1) + (gx >> 1)) * 32 + k8 * 8;
                    else
                        gi = ((long)(b * 2 + pc) * HW + (long)gy * W + gx) * 32 + k8 * 8;
                    v = *(const uint4*)(src + gi);
                }
                *(uint4*)(lds + pc * PCS + pix * 32 + ((k8 + pix) & 3) * 8) = v;
            }
        }
        __syncthreads();
        // ---- tap loop ----
#pragma unroll
        for (int dy = 0; dy < KS; ++dy) {
#pragma unroll
            for (int dx = 0; dx < KS; ++dx) {
                const int ks = ph * KK + dy * KS + dx;
                short8 a0 = ((const short8*)wf)[(ks * 2 + 0) * 64 + lane];
                short8 a1 = ((const short8*)wf)[(ks * 2 + 1) * 64 + lane];
#pragma unroll
                for (int mt = 0; mt < 2; ++mt) {
                    const int p = PB + (mt + dy) * TIW + dx;
                    const int off = p * 32 + so4[(dx + RT * (mt + dy) / 2 * 2) & 3];
                    short8 bp = *(const short8*)(lds + off);
                    short8 bc = *(const short8*)(lds + off + PCS);
                    accP[mt][0] = __builtin_amdgcn_mfma_f32_16x16x32_bf16(a0, bp, accP[mt][0], 0, 0, 0);
                    accP[mt][1] = __builtin_amdgcn_mfma_f32_16x16x32_bf16(a1, bp, accP[mt][1], 0, 0, 0);
                    accC[mt][0] = __builtin_amdgcn_mfma_f32_16x16x32_bf16(a0, bc, accC[mt][0], 0, 0, 0);
                    accC[mt][1] = __builtin_amdgcn_mfma_f32_16x16x32_bf16(a1, bc, accC[mt][1], 0, 0, 0);
                }
            }
        }
    }

    // ---- epilogue ----
    float4f b4[2], s4[2];
    b4[0] = *(const float4f*)(bias + q * 4);
    b4[1] = *(const float4f*)(bias + 16 + q * 4);
    s4[0] = *(const float4f*)(sden + q * 4);
    s4[1] = *(const float4f*)(sden + 16 + q * 4);

    if (!FUSE7) {
        // ---- fused 2x2 pool (before the bounce; accs still live) ----
        if (POOL) {
            const int W2 = W >> 1;
            const long HW4 = HW >> 2;
#pragma unroll
            for (int ct = 0; ct < 2; ++ct) {
                unsigned int pw[2], cw[2];
                unsigned short ps[4], cs[4];
#pragma unroll
                for (int r = 0; r < 4; ++r) {
                    float d0 = accC[0][ct][r], d1 = accC[1][ct][r];
                    float c00 = d0 * s4[ct][r];
                    float c10 = d1 * s4[ct][r];
                    float p00 = fmaf(accP[0][ct][r], frcp(d0 + EPSF), b4[ct][r]) * c00;
                    float p10 = fmaf(accP[1][ct][r], frcp(d1 + EPSF), b4[ct][r]) * c10;
                    float c01 = __shfl_xor(c00, 1), c11 = __shfl_xor(c10, 1);
                    float p01 = __shfl_xor(p00, 1), p11 = __shfl_xor(p10, 1);
                    float bc = c00, bp = p00;                 // first-max, row-major
                    if (c01 > bc) { bc = c01; bp = p01; }
                    if (c10 > bc) { bc = c10; bp = p10; }
                    if (c11 > bc) { bc = c11; bp = p11; }
                    ps[r] = f2bf(bp * 0.25f);
                    cs[r] = f2bf(bc * 0.25f);
                }
                if (!(n & 1)) {
                    pw[0] = (unsigned int)ps[0] | ((unsigned int)ps[1] << 16);
                    pw[1] = (unsigned int)ps[2] | ((unsigned int)ps[3] << 16);
                    cw[0] = (unsigned int)cs[0] | ((unsigned int)cs[1] << 16);
                    cw[1] = (unsigned int)cs[2] | ((unsigned int)cs[3] << 16);
                    int gy2 = (oy0 >> 1) + wv, gx2 = (ox0 >> 1) + (n >> 1);
                    long pb = ((long)gy2 * W2 + gx2) * 32 + ct * 16 + q * 4;
                    uint2 vp; vp.x = pw[0]; vp.y = pw[1];
                    uint2 vc; vc.x = cw[0]; vc.y = cw[1];
                    *(uint2*)(pout + (long)(b * 2 + 0) * HW4 * 32 + pb) = vp;
                    *(uint2*)(pout + (long)(b * 2 + 1) * HW4 * 32 + pb) = vc;
                }
            }
        }
        // ---- LDS bounce, one plane at a time; slot rotation includes n>>2
        // (pix>>2) so half-wave writes cover all 32 banks at 2/bank min ----
#pragma unroll
        for (int pl = 0; pl < 2; ++pl) {
            __syncthreads();
#pragma unroll
            for (int mt = 0; mt < 2; ++mt) {
                const int pix = (2 * wv + mt) * 16 + n;
#pragma unroll
                for (int ct = 0; ct < 2; ++ct) {
                    unsigned int w0, w1;
                    if (pl == 0) {
                        float d0 = accC[mt][ct][0], d1 = accC[mt][ct][1];
                        float d2 = accC[mt][ct][2], d3 = accC[mt][ct][3];
                        float x0 = fmaf(accP[mt][ct][0], frcp(d0 + EPSF), b4[ct][0]) * (d0 * s4[ct][0]);
                        float x1 = fmaf(accP[mt][ct][1], frcp(d1 + EPSF), b4[ct][1]) * (d1 * s4[ct][1]);
                        float x2 = fmaf(accP[mt][ct][2], frcp(d2 + EPSF), b4[ct][2]) * (d2 * s4[ct][2]);
                        float x3 = fmaf(accP[mt][ct][3], frcp(d3 + EPSF), b4[ct][3]) * (d3 * s4[ct][3]);
                        w0 = (unsigned int)f2bf(x0) | ((unsigned int)f2bf(x1) << 16);
                        w1 = (unsigned int)f2bf(x2) | ((unsigned int)f2bf(x3) << 16);
                    } else {
                        float c0 = accC[mt][ct][0] * s4[ct][0], c1 = accC[mt][ct][1] * s4[ct][1];
                        float c2 = accC[mt][ct][2] * s4[ct][2], c3 = accC[mt][ct][3] * s4[ct][3];
                        w0 = (unsigned int)f2bf(c0) | ((unsigned int)f2bf(c1) << 16);
                        w1 = (unsigned int)f2bf(c2) | ((unsigned int)f2bf(c3) << 16);
                    }
                    uint2 v; v.x = w0; v.y = w1;
                    *(uint2*)(lds + pix * 32 +
                              ((ct * 2 + (q >> 1) + n + (n >> 2)) & 3) * 8 + (q & 1) * 4) = v;
                }
            }
            __syncthreads();
            const unsigned short* obase = out + (long)(b * 2 + pl) * HW * 32;
#pragma unroll
            for (int it = 0; it < 2; ++it) {
                int off = it * 512 + tid;          // 16B units
                int pix = off >> 2, sub = off & 3;
                uint4 v = *(const uint4*)(lds + pix * 32 + ((sub + pix + (pix >> 2)) & 3) * 8);
                int ry = pix >> 4, rx = pix & 15;
                *(uint4*)(obase + ((long)(oy0 + ry) * W + ox0 + rx) * 32 + sub * 8) = v;
            }
        }
    } else {
        float4f w74[2];
        w74[0] = *(const float4f*)(w7 + q * 4);
        w74[1] = *(const float4f*)(w7 + 16 + q * 4);
        const float b7v = b7[0];
#pragma unroll
        for (int mt = 0; mt < 2; ++mt) {
            float num = 0.f, den = 0.f;
#pragma unroll
            for (int ct = 0; ct < 2; ++ct)
#pragma unroll
                for (int r = 0; r < 4; ++r) {
                    float d = accC[mt][ct][r];
                    float oxv = fmaf(accP[mt][ct][r], frcp(d + EPSF), b4[ct][r]);
                    float oc = d * s4[ct][r];
                    num = fmaf(w74[ct][r], oxv * oc, num);
                    den = fmaf(w74[ct][r], oc, den);
                }
            num += __shfl_xor(num, 16); num += __shfl_xor(num, 32);
            den += __shfl_xor(den, 16); den += __shfl_xor(den, 32);
            if (q == 0) {
                const int oy = oy0 + 2 * wv + mt;
                const int ox = ox0 + n;
                xout[(long)b * HW + (long)oy * W + ox] = fmaf(num, frcp(den + EPSF), b7v);
            }
        }
    }
}

// ---------------------------------------------------------------------------
extern "C" void kernel_launch(void* const* d_in, const int* in_sizes, int n_in,
                              void* d_out, int out_size, void* d_ws, size_t ws_size,
                              hipStream_t stream) {
    const float* x  = (const float*)d_in[0];
    const float* w1 = (const float*)d_in[1];
    const float* b1 = (const float*)d_in[2];
    const float* w2 = (const float*)d_in[3];
    const float* b2 = (const float*)d_in[4];
    const float* w3 = (const float*)d_in[5];
    const float* b3 = (const float*)d_in[6];
    const float* w4 = (const float*)d_in[7];
    const float* b4 = (const float*)d_in[8];
    const float* w5 = (const float*)d_in[9];
    const float* b5 = (const float*)d_in[10];
    const float* w6 = (const float*)d_in[11];
    const float* b6 = (const float*)d_in[12];
    const float* w7 = (const float*)d_in[13];
    const float* b7 = (const float*)d_in[14];

    const size_t HW1 = 512 * 512, HW2s = 256 * 256, HW3s = 128 * 128, HW4s = 64 * 64;

    // ---- weight arena (400000 B) ----
    const size_t WARENA = 400000;
    float* fa = (float*)d_ws;
    float *wt1 = fa;                 // 800 f
    float *s1 = wt1 + 800, *s2 = s1 + 32, *s3 = s2 + 32;   // reciprocal sums
    float *s4 = s3 + 32, *s5 = s4 + 32, *s6 = s5 + 32;     // ends at 992 f
    unsigned short* ua = (unsigned short*)((char*)d_ws + 4096);
    unsigned short *wf2 = ua;              // 25600
    unsigned short *wf3 = wf2 + 25600;     // 25600
    unsigned short *wf4 = wf3 + 25600;     // 18432
    unsigned short *wf5 = wf4 + 18432;     // 18432
    unsigned short *wf6 = wf5 + 18432;     // 18432 -> 213 KB < 400000-4096
    unsigned short* buf = (unsigned short*)((char*)d_ws + WARENA);

    // ---- stage buffers: channel-last bf16 [b*2+pc][HW][32] ----
    const size_t E1 = 2 * 2 * HW1 * 32;    // 33.55M ushort = 67.1 MB
    const size_t E2 = 2 * 2 * HW2s * 32, E3 = 2 * 2 * HW3s * 32, E4 = 2 * 2 * HW4s * 32;
    unsigned short* A = buf;
    unsigned short* B = A + E1;
    // lower-res alias inside B (sum = 22M ushorts <= E1)
    unsigned short* P = B;
    unsigned short* Q = P + E2;
    unsigned short* S = Q + E2;
    unsigned short* T = S + E3;
    unsigned short* U = T + E3;
    unsigned short* V = U + E4;

    if (ws_size < WARENA + 2 * E1 * sizeof(unsigned short)) return;  // 134.62 MB

    // ---- weight prep: single launch (frag blocks + 48 wave-sum blocks) ----
    wprep_k<<<468, 256, 0, stream>>>(w1, w2, w3, w4, w5, w6,
                                     wt1, s1, s2, s3, s4, s5, s6,
                                     wf2, wf3, wf4, wf5, wf6);

    dim3 blk(256), blkm(512);
    dim3 g1c(16, 64, 2);                               // conv1 (32x8 tiles)
    dim3 g1(32, 32, 2), g2(16, 16, 2), g3(8, 8, 2), g4(4, 4, 2);  // 16x16 tiles

    // ---- encoder ----
    conv1_k<<<g1c, blk, 0, stream>>>(x, wt1, b1, s1, A, 512, 512);
    mconv_k<5, 1, false, false><<<g1, blkm, 0, stream>>>(A, nullptr, wf2, b2, s2, B, nullptr, nullptr, nullptr, nullptr, 512, 512);
    mconv_k<5, 1, false, true><<<g1, blkm, 0, stream>>>(B, nullptr, wf3, b3, s3, A, nullptr, nullptr, nullptr, P, 512, 512);   // x1 in A, pooled -> P

    mconv_k<5, 1, false, false><<<g2, blkm, 0, stream>>>(P, nullptr, wf2, b2, s2, Q, nullptr, nullptr, nullptr, nullptr, 256, 256);
    mconv_k<5, 1, false, true><<<g2, blkm, 0, stream>>>(Q, nullptr, wf3, b3, s3, P, nullptr, nullptr, nullptr, S, 256, 256);   // x2 in P, pooled -> S

    mconv_k<5, 1, false, true><<<g3, blkm, 0, stream>>>(S, nullptr, wf2, b2, s2, T, nullptr, nullptr, nullptr, U, 128, 128);   // x3 in T, pooled -> U

    mconv_k<5, 1, false, false><<<g4, blkm, 0, stream>>>(U, nullptr, wf2, b2, s2, V, nullptr, nullptr, nullptr, nullptr, 64, 64);  // x4 in V

    // ---- decoder ----
    mconv_k<3, 2, false, false><<<g3, blkm, 0, stream>>>(T, V, wf4, b4, s4, S, nullptr, nullptr, nullptr, nullptr, 128, 128);  // x34 in S
    mconv_k<3, 2, false, false><<<g2, blkm, 0, stream>>>(P, S, wf5, b5, s5, Q, nullptr, nullptr, nullptr, nullptr, 256, 256);  // x23 in Q
    mconv_k<3, 2, true, false><<<g1, blkm, 0, stream>>>(A, Q, wf6, b6, s6, nullptr, (float*)d_out, w7, b7, nullptr, 512, 512);
}

// Round 14
// 386.938 us; speedup vs baseline: 1.9600x; 1.0153x over previous
//
#include <hip/hip_runtime.h>
#include <hip/hip_bf16.h>

#define EPSF 1e-20f

using short8  = __attribute__((ext_vector_type(8))) short;
using float4f = __attribute__((ext_vector_type(4))) float;

__device__ __forceinline__ unsigned short f2bf(float f) {
    __hip_bfloat16 h = __float2bfloat16(f);
    return __builtin_bit_cast(unsigned short, h);
}
__device__ __forceinline__ float bf2f(unsigned short u) {
    __hip_bfloat16 h = __builtin_bit_cast(__hip_bfloat16, u);
    return __bfloat162float(h);
}
__device__ __forceinline__ float frcp(float x) { return __builtin_amdgcn_rcpf(x); }

// ---------------------------------------------------------------------------
// Unified weight prep (one launch, 468 blocks):
//  blocks [0,420): linear idx
//    [0,800)      : conv1 weights -> wt1[tap*32+co] (fp32)
//    [992,107488) : MFMA A-fragments for w2..w6 (bf16, lane-exact order)
//  blocks [420,468): one WAVE per (layer,co) reciprocal weight sum
// ---------------------------------------------------------------------------
__global__ void wprep_k(const float* __restrict__ w1, const float* __restrict__ w2,
                        const float* __restrict__ w3, const float* __restrict__ w4,
                        const float* __restrict__ w5, const float* __restrict__ w6,
                        float* __restrict__ wt1,
                        float* __restrict__ is1, float* __restrict__ is2,
                        float* __restrict__ is3, float* __restrict__ is4,
                        float* __restrict__ is5, float* __restrict__ is6,
                        unsigned short* __restrict__ wf2, unsigned short* __restrict__ wf3,
                        unsigned short* __restrict__ wf4, unsigned short* __restrict__ wf5,
                        unsigned short* __restrict__ wf6) {
    const int tid = threadIdx.x;
    if (blockIdx.x >= 420) {
        int wid = (blockIdx.x - 420) * 4 + (tid >> 6);
        if (wid >= 192) return;
        int task = wid >> 5, co = wid & 31, lane = tid & 63;
        const float* w; int n; float* s;
        switch (task) {
            case 0: w = w1; n = 25;  s = is1; break;
            case 1: w = w2; n = 800; s = is2; break;
            case 2: w = w3; n = 800; s = is3; break;
            case 3: w = w4; n = 576; s = is4; break;
            case 4: w = w5; n = 576; s = is5; break;
            default: w = w6; n = 576; s = is6; break;
        }
        float acc = 0.f;
        for (int i = lane; i < n; i += 64) acc += w[co * n + i];
#pragma unroll
        for (int off = 1; off < 64; off <<= 1) acc += __shfl_xor(acc, off);
        if (lane == 0) s[co] = 1.0f / acc;
        return;
    }
    int idx = blockIdx.x * 256 + tid;
    if (idx < 800) {
        int co = idx / 25, t = idx % 25;
        wt1[t * 32 + co] = w1[idx];
        return;
    }
    if (idx < 992) return;
    int r = idx - 992;
    const float* w; unsigned short* wf; int CIN, KK, cxor;
    if (r < 25600)        {             w = w2; wf = wf2; CIN = 32; KK = 25; cxor = 0;  }
    else if (r < 51200)   { r -= 25600; w = w3; wf = wf3; CIN = 32; KK = 25; cxor = 0;  }
    else if (r < 69632)   { r -= 51200; w = w4; wf = wf4; CIN = 64; KK = 9;  cxor = 0;  }
    else if (r < 88064)   { r -= 69632; w = w5; wf = wf5; CIN = 64; KK = 9;  cxor = 0;  }
    else if (r < 106496)  { r -= 88064; w = w6; wf = wf6; CIN = 64; KK = 9;  cxor = 32; }
    else return;
    int j = r & 7, lane = (r >> 3) & 63, cot = (r >> 9) & 1, ks = r >> 10;
    int phase = ks / KK, tap = ks - phase * KK;
    int co = cot * 16 + (lane & 15);
    int ci = (phase * 32 + (lane >> 4) * 8 + j) ^ cxor;
    wf[r] = f2bf(w[((long)co * CIN + ci) * KK + tap]);
}

// ---------------------------------------------------------------------------
// conv1: CIN=1 direct VALU conv, LDS-staged. Input planar fp32
// [b][{data,conf}][H][W]; output channel-last bf16 [b*2+pc][pix][32ci].
// ---------------------------------------------------------------------------
__global__ __launch_bounds__(256)
void conv1_k(const float* __restrict__ x, const float* __restrict__ wt,
             const float* __restrict__ bias, const float* __restrict__ is_,
             unsigned short* __restrict__ out, int H, int W) {
    constexpr int TIW = 36, TIH = 12, TSZ = TIW * TIH;  // 432
    __shared__ float sc[TSZ], sp[TSZ];
    const int tid = threadIdx.x;
    const int tx = tid & 31, ty = tid >> 5;
    const int ox0 = blockIdx.x * 32, oy0 = blockIdx.y * 8, b = blockIdx.z;
    const long HW = (long)H * W;
    const float* xd = x + (long)(b * 2) * HW;
    const float* xc = xd + HW;

    for (int i = tid; i < TSZ; i += 256) {
        int py = i / TIW, px = i - py * TIW;
        int gy = oy0 - 2 + py, gx = ox0 - 2 + px;
        float c = 0.f, d = 0.f;
        if (gy >= 0 && gy < H && gx >= 0 && gx < W) {
            long g = (long)gy * W + gx;
            c = xc[g]; d = xd[g];
        }
        sc[i] = c;
        sp[i] = d * c;
    }
    __syncthreads();

    float ac[32], ap[32];
#pragma unroll
    for (int i = 0; i < 32; ++i) { ac[i] = 0.f; ap[i] = 0.f; }
#pragma unroll
    for (int dy = 0; dy < 5; ++dy) {
#pragma unroll
        for (int dx = 0; dx < 5; ++dx) {
            const int li = (ty + dy) * TIW + tx + dx;
            float cf = sc[li];
            float pv = sp[li];
            const float* wr = wt + (dy * 5 + dx) * 32;
#pragma unroll
            for (int co = 0; co < 32; ++co) {
                ac[co] = fmaf(wr[co], cf, ac[co]);
                ap[co] = fmaf(wr[co], pv, ap[co]);
            }
        }
    }

    const int xx = ox0 + tx, yy = oy0 + ty;
    unsigned short* po = out + ((long)(b * 2 + 0) * HW + (long)yy * W + xx) * 32;
    unsigned short* co_ = out + ((long)(b * 2 + 1) * HW + (long)yy * W + xx) * 32;
#pragma unroll
    for (int g = 0; g < 4; ++g) {
        uint4 vp, vc;
        unsigned int pw[4], cw[4];
#pragma unroll
        for (int h = 0; h < 4; ++h) {
            int c0 = g * 8 + h * 2, c1 = c0 + 1;
            float d0 = ac[c0], d1 = ac[c1];
            float ox0v = fmaf(ap[c0], frcp(d0 + EPSF), bias[c0]);
            float ox1v = fmaf(ap[c1], frcp(d1 + EPSF), bias[c1]);
            float oc0 = d0 * is_[c0], oc1 = d1 * is_[c1];
            pw[h] = (unsigned int)f2bf(ox0v * oc0) | ((unsigned int)f2bf(ox1v * oc1) << 16);
            cw[h] = (unsigned int)f2bf(oc0) | ((unsigned int)f2bf(oc1) << 16);
        }
        vp.x = pw[0]; vp.y = pw[1]; vp.z = pw[2]; vp.w = pw[3];
        vc.x = cw[0]; vc.y = cw[1]; vc.z = cw[2]; vc.w = cw[3];
        *(uint4*)(po + g * 8) = vp;
        *(uint4*)(co_ + g * 8) = vc;
    }
}

// ---------------------------------------------------------------------------
// MFMA implicit-GEMM nconv (channel-last bf16 [b*2+pc][y][x][32ci]).
// 16x16 output tile, 512 thr = 8 waves; wave wv owns rows {2wv,2wv+1}
// (mt = row), 16 px each. Per tap: K=32 ci in one 16x16x32 k-step.
// D: col=lane&15=pixel, row=(lane>>4)*4+reg=co. NPH=2 stages src2.
// R14 tap loop: ROW-REUSE — the mt=0 read at dy+1 is bit-identical to the
// mt=1 read at dy (same pixel, same lane). dx-outer / row-inner order with
// the previous tap's A-fragment kept live serves both mt from ONE B-read
// per row: ds_read_b128 per phase 100 -> 60 (KS=5), 36 -> 24 (KS=3); MFMA
// count unchanged. Cost: +8 VGPRs carried A-frags.
// POOL: fused 2x2 stride-2 max-pool (argmax on c, first-max row-major):
// rows mt=0/1 in-lane, columns via __shfl_xor(.,1); even-n lanes write.
// Epilogue bounces through LDS for full-line uint4 global writes (slot
// rotation includes n>>2 / pix>>2 -> 32-bank coverage). FUSE7 fuses the
// final 1x1 nconv.
// ---------------------------------------------------------------------------
template <int KS, int NPH, bool FUSE7, bool POOL>
__global__ __launch_bounds__(512, 4)
void mconv_k(const unsigned short* __restrict__ s1,
             const unsigned short* __restrict__ s2,
             const unsigned short* __restrict__ wf,
             const float* __restrict__ bias, const float* __restrict__ sden,
             unsigned short* __restrict__ out, float* __restrict__ xout,
             const float* __restrict__ w7, const float* __restrict__ b7,
             unsigned short* __restrict__ pout,
             int H, int W) {
    constexpr int R = KS / 2, KK = KS * KS;
    constexpr int TIH = 16 + KS - 1, TIW = 16 + KS - 1;   // 20 (KS=5) / 18 (KS=3)
    constexpr int RT = TIW & 3;                // 0 for KS=5, 2 for KS=3
    constexpr int PCS = TIH * TIW * 32;        // ushorts per pc-plane
    constexpr int NCH = TIH * TIW * 4;         // 16B chunks per pc-plane
    __shared__ unsigned short lds[2 * PCS];

    const int tid = threadIdx.x;
    const int wv = tid >> 6, lane = tid & 63, n = lane & 15, q = lane >> 4;
    const int ox0 = blockIdx.x * 16, oy0 = blockIdx.y * 16, b = blockIdx.z;
    const long HW = (long)H * W;

    float4f accP[2][2], accC[2][2];
#pragma unroll
    for (int mt = 0; mt < 2; ++mt)
#pragma unroll
        for (int ct = 0; ct < 2; ++ct) {
            accP[mt][ct] = (float4f)0.f;
            accC[mt][ct] = (float4f)0.f;
        }

    // per-lane swizzle-slot byte offsets: so4[j] = ((q + n + j)&3)*8
    int so4[4];
#pragma unroll
    for (int j = 0; j < 4; ++j) so4[j] = ((q + n + j) & 3) * 8;
    const int PB = (2 * wv) * TIW + n;   // lane pixel base (2 rows per wave)

    for (int ph = 0; ph < NPH; ++ph) {
        const unsigned short* src = (NPH == 2 && ph == 1) ? s2 : s1;
        if (ph) __syncthreads();
        // ---- stage tile (both pc planes) into LDS, zero-padded, swizzled ----
        for (int it = 0; it < (2 * NCH + 511) / 512; ++it) {
            int ch = it * 512 + tid;
            if (ch < 2 * NCH) {
                int pc = ch / NCH, c2 = ch - pc * NCH;
                int pix = c2 >> 2, k8 = c2 & 3;
                int py = pix / TIW, px = pix - py * TIW;
                int gy = oy0 - R + py, gx = ox0 - R + px;
                uint4 v = make_uint4(0, 0, 0, 0);
                if (gy >= 0 && gy < H && gx >= 0 && gx < W) {
                    long gi;
                    if (NPH == 2 && ph == 1)
                        gi = ((long)(b * 2 + pc) * (HW >> 2) +
                              (long)(gy >> 1) * (W >> 1) + (gx >> 1)) * 32 + k8 * 8;
                    else
                        gi = ((long)(b * 2 + pc) * HW + (long)gy * W + gx) * 32 + k8 * 8;
                    v = *(const uint4*)(src + gi);
                }
                *(uint4*)(lds + pc * PCS + pix * 32 + ((k8 + pix) & 3) * 8) = v;
            }
        }
        __syncthreads();
        // ---- tap loop: dx-outer, row-inner; one B-read serves both mt ----
#pragma unroll
        for (int dx = 0; dx < KS; ++dx) {
            short8 a0p, a1p;   // A-frags of previous row's tap (mt=1 operand)
#pragma unroll
            for (int r = 0; r < KS + 1; ++r) {
                short8 a0c, a1c;
                if (r < KS) {
                    const int ks = ph * KK + r * KS + dx;
                    a0c = ((const short8*)wf)[(ks * 2 + 0) * 64 + lane];
                    a1c = ((const short8*)wf)[(ks * 2 + 1) * 64 + lane];
                }
                const int p = PB + r * TIW + dx;
                const int off = p * 32 + so4[(dx + RT * r) & 3];
                short8 bp = *(const short8*)(lds + off);
                short8 bc = *(const short8*)(lds + off + PCS);
                if (r < KS) {   // mt=0, dy=r
                    accP[0][0] = __builtin_amdgcn_mfma_f32_16x16x32_bf16(a0c, bp, accP[0][0], 0, 0, 0);
                    accP[0][1] = __builtin_amdgcn_mfma_f32_16x16x32_bf16(a1c, bp, accP[0][1], 0, 0, 0);
                    accC[0][0] = __builtin_amdgcn_mfma_f32_16x16x32_bf16(a0c, bc, accC[0][0], 0, 0, 0);
                    accC[0][1] = __builtin_amdgcn_mfma_f32_16x16x32_bf16(a1c, bc, accC[0][1], 0, 0, 0);
                }
                if (r >= 1) {   // mt=1, dy=r-1 (A of previous row's tap)
                    accP[1][0] = __builtin_amdgcn_mfma_f32_16x16x32_bf16(a0p, bp, accP[1][0], 0, 0, 0);
                    accP[1][1] = __builtin_amdgcn_mfma_f32_16x16x32_bf16(a1p, bp, accP[1][1], 0, 0, 0);
                    accC[1][0] = __builtin_amdgcn_mfma_f32_16x16x32_bf16(a0p, bc, accC[1][0], 0, 0, 0);
                    accC[1][1] = __builtin_amdgcn_mfma_f32_16x16x32_bf16(a1p, bc, accC[1][1], 0, 0, 0);
                }
                a0p = a0c; a1p = a1c;
            }
        }
    }

    // ---- epilogue ----
    float4f b4[2], s4[2];
    b4[0] = *(const float4f*)(bias + q * 4);
    b4[1] = *(const float4f*)(bias + 16 + q * 4);
    s4[0] = *(const float4f*)(sden + q * 4);
    s4[1] = *(const float4f*)(sden + 16 + q * 4);

    if (!FUSE7) {
        // ---- fused 2x2 pool (before the bounce; accs still live) ----
        if (POOL) {
            const int W2 = W >> 1;
            const long HW4 = HW >> 2;
#pragma unroll
            for (int ct = 0; ct < 2; ++ct) {
                unsigned int pw[2], cw[2];
                unsigned short ps[4], cs[4];
#pragma unroll
                for (int r = 0; r < 4; ++r) {
                    float d0 = accC[0][ct][r], d1 = accC[1][ct][r];
                    float c00 = d0 * s4[ct][r];
                    float c10 = d1 * s4[ct][r];
                    float p00 = fmaf(accP[0][ct][r], frcp(d0 + EPSF), b4[ct][r]) * c00;
                    float p10 = fmaf(accP[1][ct][r], frcp(d1 + EPSF), b4[ct][r]) * c10;
                    float c01 = __shfl_xor(c00, 1), c11 = __shfl_xor(c10, 1);
                    float p01 = __shfl_xor(p00, 1), p11 = __shfl_xor(p10, 1);
                    float bc = c00, bp = p00;                 // first-max, row-major
                    if (c01 > bc) { bc = c01; bp = p01; }
                    if (c10 > bc) { bc = c10; bp = p10; }
                    if (c11 > bc) { bc = c11; bp = p11; }
                    ps[r] = f2bf(bp * 0.25f);
                    cs[r] = f2bf(bc * 0.25f);
                }
                if (!(n & 1)) {
                    pw[0] = (unsigned int)ps[0] | ((unsigned int)ps[1] << 16);
                    pw[1] = (unsigned int)ps[2] | ((unsigned int)ps[3] << 16);
                    cw[0] = (unsigned int)cs[0] | ((unsigned int)cs[1] << 16);
                    cw[1] = (unsigned int)cs[2] | ((unsigned int)cs[3] << 16);
                    int gy2 = (oy0 >> 1) + wv, gx2 = (ox0 >> 1) + (n >> 1);
                    long pb = ((long)gy2 * W2 + gx2) * 32 + ct * 16 + q * 4;
                    uint2 vp; vp.x = pw[0]; vp.y = pw[1];
                    uint2 vc; vc.x = cw[0]; vc.y = cw[1];
                    *(uint2*)(pout + (long)(b * 2 + 0) * HW4 * 32 + pb) = vp;
                    *(uint2*)(pout + (long)(b * 2 + 1) * HW4 * 32 + pb) = vc;
                }
            }
        }
        // ---- LDS bounce, one plane at a time ----
#pragma unroll
        for (int pl = 0; pl < 2; ++pl) {
            __syncthreads();
#pragma unroll
            for (int mt = 0; mt < 2; ++mt) {
                const int pix = (2 * wv + mt) * 16 + n;
#pragma unroll
                for (int ct = 0; ct < 2; ++ct) {
                    unsigned int w0, w1;
                    if (pl == 0) {
                        float d0 = accC[mt][ct][0], d1 = accC[mt][ct][1];
                        float d2 = accC[mt][ct][2], d3 = accC[mt][ct][3];
                        float x0 = fmaf(accP[mt][ct][0], frcp(d0 + EPSF), b4[ct][0]) * (d0 * s4[ct][0]);
                        float x1 = fmaf(accP[mt][ct][1], frcp(d1 + EPSF), b4[ct][1]) * (d1 * s4[ct][1]);
                        float x2 = fmaf(accP[mt][ct][2], frcp(d2 + EPSF), b4[ct][2]) * (d2 * s4[ct][2]);
                        float x3 = fmaf(accP[mt][ct][3], frcp(d3 + EPSF), b4[ct][3]) * (d3 * s4[ct][3]);
                        w0 = (unsigned int)f2bf(x0) | ((unsigned int)f2bf(x1) << 16);
                        w1 = (unsigned int)f2bf(x2) | ((unsigned int)f2bf(x3) << 16);
                    } else {
                        float c0 = accC[mt][ct][0] * s4[ct][0], c1 = accC[mt][ct][1] * s4[ct][1];
                        float c2 = accC[mt][ct][2] * s4[ct][2], c3 = accC[mt][ct][3] * s4[ct][3];
                        w0 = (unsigned int)f2bf(c0) | ((unsigned int)f2bf(c1) << 16);
                        w1 = (unsigned int)f2bf(c2) | ((unsigned int)f2bf(c3) << 16);
                    }
                    uint2 v; v.x = w0; v.y = w1;
                    *(uint2*)(lds + pix * 32 +
                              ((ct * 2 + (q >> 1) + n + (n >> 2)) & 3) * 8 + (q & 1) * 4) = v;
                }
            }
            __syncthreads();
            const unsigned short* obase = out + (long)(b * 2 + pl) * HW * 32;
#pragma unroll
            for (int it = 0; it < 2; ++it) {
                int off = it * 512 + tid;          // 16B units
                int pix = off >> 2, sub = off & 3;
                uint4 v = *(const uint4*)(lds + pix * 32 + ((sub + pix + (pix >> 2)) & 3) * 8);
                int ry = pix >> 4, rx = pix & 15;
                *(uint4*)(obase + ((long)(oy0 + ry) * W + ox0 + rx) * 32 + sub * 8) = v;
            }
        }
    } else {
        float4f w74[2];
        w74[0] = *(const float4f*)(w7 + q * 4);
        w74[1] = *(const float4f*)(w7 + 16 + q * 4);
        const float b7v = b7[0];
#pragma unroll
        for (int mt = 0; mt < 2; ++mt) {
            float num = 0.f, den = 0.f;
#pragma unroll
            for (int ct = 0; ct < 2; ++ct)
#pragma unroll
                for (int r = 0; r < 4; ++r) {
                    float d = accC[mt][ct][r];
                    float oxv = fmaf(accP[mt][ct][r], frcp(d + EPSF), b4[ct][r]);
                    float oc = d * s4[ct][r];
                    num = fmaf(w74[ct][r], oxv * oc, num);
                    den = fmaf(w74[ct][r], oc, den);
                }
            num += __shfl_xor(num, 16); num += __shfl_xor(num, 32);
            den += __shfl_xor(den, 16); den += __shfl_xor(den, 32);
            if (q == 0) {
                const int oy = oy0 + 2 * wv + mt;
                const int ox = ox0 + n;
                xout[(long)b * HW + (long)oy * W + ox] = fmaf(num, frcp(den + EPSF), b7v);
            }
        }
    }
}

// ---------------------------------------------------------------------------
extern "C" void kernel_launch(void* const* d_in, const int* in_sizes, int n_in,
                              void* d_out, int out_size, void* d_ws, size_t ws_size,
                              hipStream_t stream) {
    const float* x  = (const float*)d_in[0];
    const float* w1 = (const float*)d_in[1];
    const float* b1 = (const float*)d_in[2];
    const float* w2 = (const float*)d_in[3];
    const float* b2 = (const float*)d_in[4];
    const float* w3 = (const float*)d_in[5];
    const float* b3 = (const float*)d_in[6];
    const float* w4 = (const float*)d_in[7];
    const float* b4 = (const float*)d_in[8];
    const float* w5 = (const float*)d_in[9];
    const float* b5 = (const float*)d_in[10];
    const float* w6 = (const float*)d_in[11];
    const float* b6 = (const float*)d_in[12];
    const float* w7 = (const float*)d_in[13];
    const float* b7 = (const float*)d_in[14];

    const size_t HW1 = 512 * 512, HW2s = 256 * 256, HW3s = 128 * 128, HW4s = 64 * 64;

    // ---- weight arena (400000 B) ----
    const size_t WARENA = 400000;
    float* fa = (float*)d_ws;
    float *wt1 = fa;                 // 800 f
    float *s1 = wt1 + 800, *s2 = s1 + 32, *s3 = s2 + 32;   // reciprocal sums
    float *s4 = s3 + 32, *s5 = s4 + 32, *s6 = s5 + 32;     // ends at 992 f
    unsigned short* ua = (unsigned short*)((char*)d_ws + 4096);
    unsigned short *wf2 = ua;              // 25600
    unsigned short *wf3 = wf2 + 25600;     // 25600
    unsigned short *wf4 = wf3 + 25600;     // 18432
    unsigned short *wf5 = wf4 + 18432;     // 18432
    unsigned short *wf6 = wf5 + 18432;     // 18432 -> 213 KB < 400000-4096
    unsigned short* buf = (unsigned short*)((char*)d_ws + WARENA);

    // ---- stage buffers: channel-last bf16 [b*2+pc][HW][32] ----
    const size_t E1 = 2 * 2 * HW1 * 32;    // 33.55M ushort = 67.1 MB
    const size_t E2 = 2 * 2 * HW2s * 32, E3 = 2 * 2 * HW3s * 32, E4 = 2 * 2 * HW4s * 32;
    unsigned short* A = buf;
    unsigned short* B = A + E1;
    // lower-res alias inside B (sum = 22M ushorts <= E1)
    unsigned short* P = B;
    unsigned short* Q = P + E2;
    unsigned short* S = Q + E2;
    unsigned short* T = S + E3;
    unsigned short* U = T + E3;
    unsigned short* V = U + E4;

    if (ws_size < WARENA + 2 * E1 * sizeof(unsigned short)) return;  // 134.62 MB

    // ---- weight prep: single launch (frag blocks + 48 wave-sum blocks) ----
    wprep_k<<<468, 256, 0, stream>>>(w1, w2, w3, w4, w5, w6,
                                     wt1, s1, s2, s3, s4, s5, s6,
                                     wf2, wf3, wf4, wf5, wf6);

    dim3 blk(256), blkm(512);
    dim3 g1c(16, 64, 2);                               // conv1 (32x8 tiles)
    dim3 g1(32, 32, 2), g2(16, 16, 2), g3(8, 8, 2), g4(4, 4, 2);  // 16x16 tiles

    // ---- encoder ----
    conv1_k<<<g1c, blk, 0, stream>>>(x, wt1, b1, s1, A, 512, 512);
    mconv_k<5, 1, false, false><<<g1, blkm, 0, stream>>>(A, nullptr, wf2, b2, s2, B, nullptr, nullptr, nullptr, nullptr, 512, 512);
    mconv_k<5, 1, false, true><<<g1, blkm, 0, stream>>>(B, nullptr, wf3, b3, s3, A, nullptr, nullptr, nullptr, P, 512, 512);   // x1 in A, pooled -> P

    mconv_k<5, 1, false, false><<<g2, blkm, 0, stream>>>(P, nullptr, wf2, b2, s2, Q, nullptr, nullptr, nullptr, nullptr, 256, 256);
    mconv_k<5, 1, false, true><<<g2, blkm, 0, stream>>>(Q, nullptr, wf3, b3, s3, P, nullptr, nullptr, nullptr, S, 256, 256);   // x2 in P, pooled -> S

    mconv_k<5, 1, false, true><<<g3, blkm, 0, stream>>>(S, nullptr, wf2, b2, s2, T, nullptr, nullptr, nullptr, U, 128, 128);   // x3 in T, pooled -> U

    mconv_k<5, 1, false, false><<<g4, blkm, 0, stream>>>(U, nullptr, wf2, b2, s2, V, nullptr, nullptr, nullptr, nullptr, 64, 64);  // x4 in V

    // ---- decoder ----
    mconv_k<3, 2, false, false><<<g3, blkm, 0, stream>>>(T, V, wf4, b4, s4, S, nullptr, nullptr, nullptr, nullptr, 128, 128);  // x34 in S
    mconv_k<3, 2, false, false><<<g2, blkm, 0, stream>>>(P, S, wf5, b5, s5, Q, nullptr, nullptr, nullptr, nullptr, 256, 256);  // x23 in Q
    mconv_k<3, 2, true, false><<<g1, blkm, 0, stream>>>(A, Q, wf6, b6, s6, nullptr, (float*)d_out, w7, b7, nullptr, 512, 512);
}

// Round 15
// 385.969 us; speedup vs baseline: 1.9649x; 1.0025x over previous
//
#include <hip/hip_runtime.h>
#include <hip/hip_bf16.h>

#define EPSF 1e-20f

using short8  = __attribute__((ext_vector_type(8))) short;
using float4f = __attribute__((ext_vector_type(4))) float;

__device__ __forceinline__ unsigned short f2bf(float f) {
    __hip_bfloat16 h = __float2bfloat16(f);
    return __builtin_bit_cast(unsigned short, h);
}
__device__ __forceinline__ float bf2f(unsigned short u) {
    __hip_bfloat16 h = __builtin_bit_cast(__hip_bfloat16, u);
    return __bfloat162float(h);
}
__device__ __forceinline__ float frcp(float x) { return __builtin_amdgcn_rcpf(x); }

// ---------------------------------------------------------------------------
// Unified weight prep (one launch, 468 blocks):
//  blocks [0,420): linear idx
//    [0,800)      : conv1 weights -> wt1[tap*32+co] (fp32)
//    [992,107488) : MFMA A-fragments for w2..w6 (bf16, lane-exact order)
//  blocks [420,468): one WAVE per (layer,co) reciprocal weight sum
// ---------------------------------------------------------------------------
__global__ void wprep_k(const float* __restrict__ w1, const float* __restrict__ w2,
                        const float* __restrict__ w3, const float* __restrict__ w4,
                        const float* __restrict__ w5, const float* __restrict__ w6,
                        float* __restrict__ wt1,
                        float* __restrict__ is1, float* __restrict__ is2,
                        float* __restrict__ is3, float* __restrict__ is4,
                        float* __restrict__ is5, float* __restrict__ is6,
                        unsigned short* __restrict__ wf2, unsigned short* __restrict__ wf3,
                        unsigned short* __restrict__ wf4, unsigned short* __restrict__ wf5,
                        unsigned short* __restrict__ wf6) {
    const int tid = threadIdx.x;
    if (blockIdx.x >= 420) {
        int wid = (blockIdx.x - 420) * 4 + (tid >> 6);
        if (wid >= 192) return;
        int task = wid >> 5, co = wid & 31, lane = tid & 63;
        const float* w; int n; float* s;
        switch (task) {
            case 0: w = w1; n = 25;  s = is1; break;
            case 1: w = w2; n = 800; s = is2; break;
            case 2: w = w3; n = 800; s = is3; break;
            case 3: w = w4; n = 576; s = is4; break;
            case 4: w = w5; n = 576; s = is5; break;
            default: w = w6; n = 576; s = is6; break;
        }
        float acc = 0.f;
        for (int i = lane; i < n; i += 64) acc += w[co * n + i];
#pragma unroll
        for (int off = 1; off < 64; off <<= 1) acc += __shfl_xor(acc, off);
        if (lane == 0) s[co] = 1.0f / acc;
        return;
    }
    int idx = blockIdx.x * 256 + tid;
    if (idx < 800) {
        int co = idx / 25, t = idx % 25;
        wt1[t * 32 + co] = w1[idx];
        return;
    }
    if (idx < 992) return;
    int r = idx - 992;
    const float* w; unsigned short* wf; int CIN, KK, cxor;
    if (r < 25600)        {             w = w2; wf = wf2; CIN = 32; KK = 25; cxor = 0;  }
    else if (r < 51200)   { r -= 25600; w = w3; wf = wf3; CIN = 32; KK = 25; cxor = 0;  }
    else if (r < 69632)   { r -= 51200; w = w4; wf = wf4; CIN = 64; KK = 9;  cxor = 0;  }
    else if (r < 88064)   { r -= 69632; w = w5; wf = wf5; CIN = 64; KK = 9;  cxor = 0;  }
    else if (r < 106496)  { r -= 88064; w = w6; wf = wf6; CIN = 64; KK = 9;  cxor = 32; }
    else return;
    int j = r & 7, lane = (r >> 3) & 63, cot = (r >> 9) & 1, ks = r >> 10;
    int phase = ks / KK, tap = ks - phase * KK;
    int co = cot * 16 + (lane & 15);
    int ci = (phase * 32 + (lane >> 4) * 8 + j) ^ cxor;
    wf[r] = f2bf(w[((long)co * CIN + ci) * KK + tap]);
}

// ---------------------------------------------------------------------------
// conv1: CIN=1 direct VALU conv, LDS-staged. Input planar fp32
// [b][{data,conf}][H][W]; output channel-last bf16 [b*2+pc][pix][32ci].
// ---------------------------------------------------------------------------
__global__ __launch_bounds__(256)
void conv1_k(const float* __restrict__ x, const float* __restrict__ wt,
             const float* __restrict__ bias, const float* __restrict__ is_,
             unsigned short* __restrict__ out, int H, int W) {
    constexpr int TIW = 36, TIH = 12, TSZ = TIW * TIH;  // 432
    __shared__ float sc[TSZ], sp[TSZ];
    const int tid = threadIdx.x;
    const int tx = tid & 31, ty = tid >> 5;
    const int ox0 = blockIdx.x * 32, oy0 = blockIdx.y * 8, b = blockIdx.z;
    const long HW = (long)H * W;
    const float* xd = x + (long)(b * 2) * HW;
    const float* xc = xd + HW;

    for (int i = tid; i < TSZ; i += 256) {
        int py = i / TIW, px = i - py * TIW;
        int gy = oy0 - 2 + py, gx = ox0 - 2 + px;
        float c = 0.f, d = 0.f;
        if (gy >= 0 && gy < H && gx >= 0 && gx < W) {
            long g = (long)gy * W + gx;
            c = xc[g]; d = xd[g];
        }
        sc[i] = c;
        sp[i] = d * c;
    }
    __syncthreads();

    float ac[32], ap[32];
#pragma unroll
    for (int i = 0; i < 32; ++i) { ac[i] = 0.f; ap[i] = 0.f; }
#pragma unroll
    for (int dy = 0; dy < 5; ++dy) {
#pragma unroll
        for (int dx = 0; dx < 5; ++dx) {
            const int li = (ty + dy) * TIW + tx + dx;
            float cf = sc[li];
            float pv = sp[li];
            const float* wr = wt + (dy * 5 + dx) * 32;
#pragma unroll
            for (int co = 0; co < 32; ++co) {
                ac[co] = fmaf(wr[co], cf, ac[co]);
                ap[co] = fmaf(wr[co], pv, ap[co]);
            }
        }
    }

    const int xx = ox0 + tx, yy = oy0 + ty;
    unsigned short* po = out + ((long)(b * 2 + 0) * HW + (long)yy * W + xx) * 32;
    unsigned short* co_ = out + ((long)(b * 2 + 1) * HW + (long)yy * W + xx) * 32;
#pragma unroll
    for (int g = 0; g < 4; ++g) {
        uint4 vp, vc;
        unsigned int pw[4], cw[4];
#pragma unroll
        for (int h = 0; h < 4; ++h) {
            int c0 = g * 8 + h * 2, c1 = c0 + 1;
            float d0 = ac[c0], d1 = ac[c1];
            float ox0v = fmaf(ap[c0], frcp(d0 + EPSF), bias[c0]);
            float ox1v = fmaf(ap[c1], frcp(d1 + EPSF), bias[c1]);
            float oc0 = d0 * is_[c0], oc1 = d1 * is_[c1];
            pw[h] = (unsigned int)f2bf(ox0v * oc0) | ((unsigned int)f2bf(ox1v * oc1) << 16);
            cw[h] = (unsigned int)f2bf(oc0) | ((unsigned int)f2bf(oc1) << 16);
        }
        vp.x = pw[0]; vp.y = pw[1]; vp.z = pw[2]; vp.w = pw[3];
        vc.x = cw[0]; vc.y = cw[1]; vc.z = cw[2]; vc.w = cw[3];
        *(uint4*)(po + g * 8) = vp;
        *(uint4*)(co_ + g * 8) = vc;
    }
}

// ---------------------------------------------------------------------------
// MFMA implicit-GEMM nconv (channel-last bf16 [b*2+pc][y][x][32ci]).
// R15: 16x8 output tile, 256 thr = 4 waves; wave wv owns rows {2wv,2wv+1}
// (mt = row), 16 px each — identical per-wave work to R14, but LDS drops to
// 30.7 KB (KS=5) / 23 KB (KS=3) so >=4-5 blocks/CU fit. This tests the
// R10-R14 anomaly: OccupancyPercent pinned at ~38% (12 waves/CU) despite
// LDS shrink 55.3->51.2 KB — i.e. a third block never became resident.
// Cost: halo fetch ratio 1.56 -> 1.88 (HBM at 24%, harmless).
// Tap loop: ROW-REUSE (dx-outer / row-inner, one B-read serves both mt).
// Per tap: K=32 ci in one 16x16x32 k-step. D: col=lane&15=pixel,
// row=(lane>>4)*4+reg=co. NPH=2 stages src2 (half-res, up2'd in staging).
// POOL: fused 2x2 stride-2 max-pool (argmax on c, first-max row-major):
// rows mt=0/1 in-lane, columns via __shfl_xor(.,1); even-n lanes write.
// Epilogue bounces through LDS for full-line uint4 global writes. FUSE7
// fuses the final 1x1 nconv.
// ---------------------------------------------------------------------------
template <int KS, int NPH, bool FUSE7, bool POOL>
__global__ __launch_bounds__(256, 4)
void mconv_k(const unsigned short* __restrict__ s1,
             const unsigned short* __restrict__ s2,
             const unsigned short* __restrict__ wf,
             const float* __restrict__ bias, const float* __restrict__ sden,
             unsigned short* __restrict__ out, float* __restrict__ xout,
             const float* __restrict__ w7, const float* __restrict__ b7,
             unsigned short* __restrict__ pout,
             int H, int W) {
    constexpr int R = KS / 2, KK = KS * KS;
    constexpr int TIH = 8 + KS - 1, TIW = 16 + KS - 1;    // 12x20 (KS=5) / 10x18 (KS=3)
    constexpr int RT = TIW & 3;                // 0 for KS=5, 2 for KS=3
    constexpr int PCS = TIH * TIW * 32;        // ushorts per pc-plane
    constexpr int NCH = TIH * TIW * 4;         // 16B chunks per pc-plane
    __shared__ unsigned short lds[2 * PCS];

    const int tid = threadIdx.x;
    const int wv = tid >> 6, lane = tid & 63, n = lane & 15, q = lane >> 4;
    const int ox0 = blockIdx.x * 16, oy0 = blockIdx.y * 8, b = blockIdx.z;
    const long HW = (long)H * W;

    float4f accP[2][2], accC[2][2];
#pragma unroll
    for (int mt = 0; mt < 2; ++mt)
#pragma unroll
        for (int ct = 0; ct < 2; ++ct) {
            accP[mt][ct] = (float4f)0.f;
            accC[mt][ct] = (float4f)0.f;
        }

    // per-lane swizzle-slot byte offsets: so4[j] = ((q + n + j)&3)*8
    int so4[4];
#pragma unroll
    for (int j = 0; j < 4; ++j) so4[j] = ((q + n + j) & 3) * 8;
    const int PB = (2 * wv) * TIW + n;   // lane pixel base (2 rows per wave)

    for (int ph = 0; ph < NPH; ++ph) {
        const unsigned short* src = (NPH == 2 && ph == 1) ? s2 : s1;
        if (ph) __syncthreads();
        // ---- stage tile (both pc planes) into LDS, zero-padded, swizzled ----
        for (int it = 0; it < (2 * NCH + 255) / 256; ++it) {
            int ch = it * 256 + tid;
            if (ch < 2 * NCH) {
                int pc = ch / NCH, c2 = ch - pc * NCH;
                int pix = c2 >> 2, k8 = c2 & 3;
                int py = pix / TIW, px = pix - py * TIW;
                int gy = oy0 - R + py, gx = ox0 - R + px;
                uint4 v = make_uint4(0, 0, 0, 0);
                if (gy >= 0 && gy < H && gx >= 0 && gx < W) {
                    long gi;
                    if (NPH == 2 && ph == 1)
                        gi = ((long)(b * 2 + pc) * (HW >> 2) +
                              (long)(gy >> 1) * (W >> 1) + (gx >> 1)) * 32 + k8 * 8;
                    else
                        gi = ((long)(b * 2 + pc) * HW + (long)gy * W + gx) * 32 + k8 * 8;
                    v = *(const uint4*)(src + gi);
                }
                *(uint4*)(lds + pc * PCS + pix * 32 + ((k8 + pix) & 3) * 8) = v;
            }
        }
        __syncthreads();
        // ---- tap loop: dx-outer, row-inner; one B-read serves both mt ----
#pragma unroll
        for (int dx = 0; dx < KS; ++dx) {
            short8 a0p, a1p;   // A-frags of previous row's tap (mt=1 operand)
#pragma unroll
            for (int r = 0; r < KS + 1; ++r) {
                short8 a0c, a1c;
                if (r < KS) {
                    const int ks = ph * KK + r * KS + dx;
                    a0c = ((const short8*)wf)[(ks * 2 + 0) * 64 + lane];
                    a1c = ((const short8*)wf)[(ks * 2 + 1) * 64 + lane];
                }
                const int p = PB + r * TIW + dx;
                const int off = p * 32 + so4[(dx + RT * r) & 3];
                short8 bp = *(const short8*)(lds + off);
                short8 bc = *(const short8*)(lds + off + PCS);
                if (r < KS) {   // mt=0, dy=r
                    accP[0][0] = __builtin_amdgcn_mfma_f32_16x16x32_bf16(a0c, bp, accP[0][0], 0, 0, 0);
                    accP[0][1] = __builtin_amdgcn_mfma_f32_16x16x32_bf16(a1c, bp, accP[0][1], 0, 0, 0);
                    accC[0][0] = __builtin_amdgcn_mfma_f32_16x16x32_bf16(a0c, bc, accC[0][0], 0, 0, 0);
                    accC[0][1] = __builtin_amdgcn_mfma_f32_16x16x32_bf16(a1c, bc, accC[0][1], 0, 0, 0);
                }
                if (r >= 1) {   // mt=1, dy=r-1 (A of previous row's tap)
                    accP[1][0] = __builtin_amdgcn_mfma_f32_16x16x32_bf16(a0p, bp, accP[1][0], 0, 0, 0);
                    accP[1][1] = __builtin_amdgcn_mfma_f32_16x16x32_bf16(a1p, bp, accP[1][1], 0, 0, 0);
                    accC[1][0] = __builtin_amdgcn_mfma_f32_16x16x32_bf16(a0p, bc, accC[1][0], 0, 0, 0);
                    accC[1][1] = __builtin_amdgcn_mfma_f32_16x16x32_bf16(a1p, bc, accC[1][1], 0, 0, 0);
                }
                a0p = a0c; a1p = a1c;
            }
        }
    }

    // ---- epilogue ----
    float4f b4[2], s4[2];
    b4[0] = *(const float4f*)(bias + q * 4);
    b4[1] = *(const float4f*)(bias + 16 + q * 4);
    s4[0] = *(const float4f*)(sden + q * 4);
    s4[1] = *(const float4f*)(sden + 16 + q * 4);

    if (!FUSE7) {
        // ---- fused 2x2 pool (before the bounce; accs still live) ----
        if (POOL) {
            const int W2 = W >> 1;
            const long HW4 = HW >> 2;
#pragma unroll
            for (int ct = 0; ct < 2; ++ct) {
                unsigned int pw[2], cw[2];
                unsigned short ps[4], cs[4];
#pragma unroll
                for (int r = 0; r < 4; ++r) {
                    float d0 = accC[0][ct][r], d1 = accC[1][ct][r];
                    float c00 = d0 * s4[ct][r];
                    float c10 = d1 * s4[ct][r];
                    float p00 = fmaf(accP[0][ct][r], frcp(d0 + EPSF), b4[ct][r]) * c00;
                    float p10 = fmaf(accP[1][ct][r], frcp(d1 + EPSF), b4[ct][r]) * c10;
                    float c01 = __shfl_xor(c00, 1), c11 = __shfl_xor(c10, 1);
                    float p01 = __shfl_xor(p00, 1), p11 = __shfl_xor(p10, 1);
                    float bc = c00, bp = p00;                 // first-max, row-major
                    if (c01 > bc) { bc = c01; bp = p01; }
                    if (c10 > bc) { bc = c10; bp = p10; }
                    if (c11 > bc) { bc = c11; bp = p11; }
                    ps[r] = f2bf(bp * 0.25f);
                    cs[r] = f2bf(bc * 0.25f);
                }
                if (!(n & 1)) {
                    pw[0] = (unsigned int)ps[0] | ((unsigned int)ps[1] << 16);
                    pw[1] = (unsigned int)ps[2] | ((unsigned int)ps[3] << 16);
                    cw[0] = (unsigned int)cs[0] | ((unsigned int)cs[1] << 16);
                    cw[1] = (unsigned int)cs[2] | ((unsigned int)cs[3] << 16);
                    int gy2 = (oy0 >> 1) + wv, gx2 = (ox0 >> 1) + (n >> 1);
                    long pb = ((long)gy2 * W2 + gx2) * 32 + ct * 16 + q * 4;
                    uint2 vp; vp.x = pw[0]; vp.y = pw[1];
                    uint2 vc; vc.x = cw[0]; vc.y = cw[1];
                    *(uint2*)(pout + (long)(b * 2 + 0) * HW4 * 32 + pb) = vp;
                    *(uint2*)(pout + (long)(b * 2 + 1) * HW4 * 32 + pb) = vc;
                }
            }
        }
        // ---- LDS bounce, one plane at a time ----
#pragma unroll
        for (int pl = 0; pl < 2; ++pl) {
            __syncthreads();
#pragma unroll
            for (int mt = 0; mt < 2; ++mt) {
                const int pix = (2 * wv + mt) * 16 + n;
#pragma unroll
                for (int ct = 0; ct < 2; ++ct) {
                    unsigned int w0, w1;
                    if (pl == 0) {
                        float d0 = accC[mt][ct][0], d1 = accC[mt][ct][1];
                        float d2 = accC[mt][ct][2], d3 = accC[mt][ct][3];
                        float x0 = fmaf(accP[mt][ct][0], frcp(d0 + EPSF), b4[ct][0]) * (d0 * s4[ct][0]);
                        float x1 = fmaf(accP[mt][ct][1], frcp(d1 + EPSF), b4[ct][1]) * (d1 * s4[ct][1]);
                        float x2 = fmaf(accP[mt][ct][2], frcp(d2 + EPSF), b4[ct][2]) * (d2 * s4[ct][2]);
                        float x3 = fmaf(accP[mt][ct][3], frcp(d3 + EPSF), b4[ct][3]) * (d3 * s4[ct][3]);
                        w0 = (unsigned int)f2bf(x0) | ((unsigned int)f2bf(x1) << 16);
                        w1 = (unsigned int)f2bf(x2) | ((unsigned int)f2bf(x3) << 16);
                    } else {
                        float c0 = accC[mt][ct][0] * s4[ct][0], c1 = accC[mt][ct][1] * s4[ct][1];
                        float c2 = accC[mt][ct][2] * s4[ct][2], c3 = accC[mt][ct][3] * s4[ct][3];
                        w0 = (unsigned int)f2bf(c0) | ((unsigned int)f2bf(c1) << 16);
                        w1 = (unsigned int)f2bf(c2) | ((unsigned int)f2bf(c3) << 16);
                    }
                    uint2 v; v.x = w0; v.y = w1;
                    *(uint2*)(lds + pix * 32 +
                              ((ct * 2 + (q >> 1) + n + (n >> 2)) & 3) * 8 + (q & 1) * 4) = v;
                }
            }
            __syncthreads();
            // 128 px * 64B = 8 KB -> 512 uint4 -> 2 iterations of 256 thr
            const unsigned short* obase = out + (long)(b * 2 + pl) * HW * 32;
#pragma unroll
            for (int it = 0; it < 2; ++it) {
                int off = it * 256 + tid;          // 16B units
                int pix = off >> 2, sub = off & 3;
                uint4 v = *(const uint4*)(lds + pix * 32 + ((sub + pix + (pix >> 2)) & 3) * 8);
                int ry = pix >> 4, rx = pix & 15;
                *(uint4*)(obase + ((long)(oy0 + ry) * W + ox0 + rx) * 32 + sub * 8) = v;
            }
        }
    } else {
        float4f w74[2];
        w74[0] = *(const float4f*)(w7 + q * 4);
        w74[1] = *(const float4f*)(w7 + 16 + q * 4);
        const float b7v = b7[0];
#pragma unroll
        for (int mt = 0; mt < 2; ++mt) {
            float num = 0.f, den = 0.f;
#pragma unroll
            for (int ct = 0; ct < 2; ++ct)
#pragma unroll
                for (int r = 0; r < 4; ++r) {
                    float d = accC[mt][ct][r];
                    float oxv = fmaf(accP[mt][ct][r], frcp(d + EPSF), b4[ct][r]);
                    float oc = d * s4[ct][r];
                    num = fmaf(w74[ct][r], oxv * oc, num);
                    den = fmaf(w74[ct][r], oc, den);
                }
            num += __shfl_xor(num, 16); num += __shfl_xor(num, 32);
            den += __shfl_xor(den, 16); den += __shfl_xor(den, 32);
            if (q == 0) {
                const int oy = oy0 + 2 * wv + mt;
                const int ox = ox0 + n;
                xout[(long)b * HW + (long)oy * W + ox] = fmaf(num, frcp(den + EPSF), b7v);
            }
        }
    }
}

// ---------------------------------------------------------------------------
extern "C" void kernel_launch(void* const* d_in, const int* in_sizes, int n_in,
                              void* d_out, int out_size, void* d_ws, size_t ws_size,
                              hipStream_t stream) {
    const float* x  = (const float*)d_in[0];
    const float* w1 = (const float*)d_in[1];
    const float* b1 = (const float*)d_in[2];
    const float* w2 = (const float*)d_in[3];
    const float* b2 = (const float*)d_in[4];
    const float* w3 = (const float*)d_in[5];
    const float* b3 = (const float*)d_in[6];
    const float* w4 = (const float*)d_in[7];
    const float* b4 = (const float*)d_in[8];
    const float* w5 = (const float*)d_in[9];
    const float* b5 = (const float*)d_in[10];
    const float* w6 = (const float*)d_in[11];
    const float* b6 = (const float*)d_in[12];
    const float* w7 = (const float*)d_in[13];
    const float* b7 = (const float*)d_in[14];

    const size_t HW1 = 512 * 512, HW2s = 256 * 256, HW3s = 128 * 128, HW4s = 64 * 64;

    // ---- weight arena (400000 B) ----
    const size_t WARENA = 400000;
    float* fa = (float*)d_ws;
    float *wt1 = fa;                 // 800 f
    float *s1 = wt1 + 800, *s2 = s1 + 32, *s3 = s2 + 32;   // reciprocal sums
    float *s4 = s3 + 32, *s5 = s4 + 32, *s6 = s5 + 32;     // ends at 992 f
    unsigned short* ua = (unsigned short*)((char*)d_ws + 4096);
    unsigned short *wf2 = ua;              // 25600
    unsigned short *wf3 = wf2 + 25600;     // 25600
    unsigned short *wf4 = wf3 + 25600;     // 18432
    unsigned short *wf5 = wf4 + 18432;     // 18432
    unsigned short *wf6 = wf5 + 18432;     // 18432 -> 213 KB < 400000-4096
    unsigned short* buf = (unsigned short*)((char*)d_ws + WARENA);

    // ---- stage buffers: channel-last bf16 [b*2+pc][HW][32] ----
    const size_t E1 = 2 * 2 * HW1 * 32;    // 33.55M ushort = 67.1 MB
    const size_t E2 = 2 * 2 * HW2s * 32, E3 = 2 * 2 * HW3s * 32, E4 = 2 * 2 * HW4s * 32;
    unsigned short* A = buf;
    unsigned short* B = A + E1;
    // lower-res alias inside B (sum = 22M ushorts <= E1)
    unsigned short* P = B;
    unsigned short* Q = P + E2;
    unsigned short* S = Q + E2;
    unsigned short* T = S + E3;
    unsigned short* U = T + E3;
    unsigned short* V = U + E4;

    if (ws_size < WARENA + 2 * E1 * sizeof(unsigned short)) return;  // 134.62 MB

    // ---- weight prep: single launch (frag blocks + 48 wave-sum blocks) ----
    wprep_k<<<468, 256, 0, stream>>>(w1, w2, w3, w4, w5, w6,
                                     wt1, s1, s2, s3, s4, s5, s6,
                                     wf2, wf3, wf4, wf5, wf6);

    dim3 blkm(256);
    dim3 g1c(16, 64, 2);                               // conv1 (32x8 tiles)
    dim3 g1(32, 64, 2), g2(16, 32, 2), g3(8, 16, 2), g4(4, 8, 2);  // 16x8 tiles

    // ---- encoder ----
    conv1_k<<<g1c, blkm, 0, stream>>>(x, wt1, b1, s1, A, 512, 512);
    mconv_k<5, 1, false, false><<<g1, blkm, 0, stream>>>(A, nullptr, wf2, b2, s2, B, nullptr, nullptr, nullptr, nullptr, 512, 512);
    mconv_k<5, 1, false, true><<<g1, blkm, 0, stream>>>(B, nullptr, wf3, b3, s3, A, nullptr, nullptr, nullptr, P, 512, 512);   // x1 in A, pooled -> P

    mconv_k<5, 1, false, false><<<g2, blkm, 0, stream>>>(P, nullptr, wf2, b2, s2, Q, nullptr, nullptr, nullptr, nullptr, 256, 256);
    mconv_k<5, 1, false, true><<<g2, blkm, 0, stream>>>(Q, nullptr, wf3, b3, s3, P, nullptr, nullptr, nullptr, S, 256, 256);   // x2 in P, pooled -> S

    mconv_k<5, 1, false, true><<<g3, blkm, 0, stream>>>(S, nullptr, wf2, b2, s2, T, nullptr, nullptr, nullptr, U, 128, 128);   // x3 in T, pooled -> U

    mconv_k<5, 1, false, false><<<g4, blkm, 0, stream>>>(U, nullptr, wf2, b2, s2, V, nullptr, nullptr, nullptr, nullptr, 64, 64);  // x4 in V

    // ---- decoder ----
    mconv_k<3, 2, false, false><<<g3, blkm, 0, stream>>>(T, V, wf4, b4, s4, S, nullptr, nullptr, nullptr, nullptr, 128, 128);  // x34 in S
    mconv_k<3, 2, false, false><<<g2, blkm, 0, stream>>>(P, S, wf5, b5, s5, Q, nullptr, nullptr, nullptr, nullptr, 256, 256);  // x23 in Q
    mconv_k<3, 2, true, false><<<g1, blkm, 0, stream>>>(A, Q, wf6, b6, s6, nullptr, (float*)d_out, w7, b7, nullptr, 512, 512);
}

// Round 16
// 371.938 us; speedup vs baseline: 2.0390x; 1.0377x over previous
//
#include <hip/hip_runtime.h>
#include <hip/hip_bf16.h>

#define EPSF 1e-20f

using short8  = __attribute__((ext_vector_type(8))) short;
using float4f = __attribute__((ext_vector_type(4))) float;
typedef const __attribute__((address_space(1))) unsigned int* gas_t;
typedef __attribute__((address_space(3))) unsigned int* las_t;

__device__ __forceinline__ unsigned short f2bf(float f) {
    __hip_bfloat16 h = __float2bfloat16(f);
    return __builtin_bit_cast(unsigned short, h);
}
__device__ __forceinline__ float bf2f(unsigned short u) {
    __hip_bfloat16 h = __builtin_bit_cast(__hip_bfloat16, u);
    return __bfloat162float(h);
}
__device__ __forceinline__ float frcp(float x) { return __builtin_amdgcn_rcpf(x); }

// ---------------------------------------------------------------------------
// Unified weight prep (one launch, 468 blocks):
//  blocks [0,420): linear idx
//    [0,800)      : conv1 weights -> wt1[tap*32+co] (fp32)
//    [992,107488) : MFMA A-fragments for w2..w6 (bf16, lane-exact order)
//  blocks [420,468): one WAVE per (layer,co) reciprocal weight sum
//  block 0 also zeroes the 16-B zero page (OOB target for global_load_lds).
// ---------------------------------------------------------------------------
__global__ void wprep_k(const float* __restrict__ w1, const float* __restrict__ w2,
                        const float* __restrict__ w3, const float* __restrict__ w4,
                        const float* __restrict__ w5, const float* __restrict__ w6,
                        float* __restrict__ wt1,
                        float* __restrict__ is1, float* __restrict__ is2,
                        float* __restrict__ is3, float* __restrict__ is4,
                        float* __restrict__ is5, float* __restrict__ is6,
                        unsigned short* __restrict__ wf2, unsigned short* __restrict__ wf3,
                        unsigned short* __restrict__ wf4, unsigned short* __restrict__ wf5,
                        unsigned short* __restrict__ wf6,
                        unsigned int* __restrict__ zpage) {
    const int tid = threadIdx.x;
    if (blockIdx.x == 0 && tid < 4) zpage[tid] = 0;   // 16-B zero page
    if (blockIdx.x >= 420) {
        int wid = (blockIdx.x - 420) * 4 + (tid >> 6);
        if (wid >= 192) return;
        int task = wid >> 5, co = wid & 31, lane = tid & 63;
        const float* w; int n; float* s;
        switch (task) {
            case 0: w = w1; n = 25;  s = is1; break;
            case 1: w = w2; n = 800; s = is2; break;
            case 2: w = w3; n = 800; s = is3; break;
            case 3: w = w4; n = 576; s = is4; break;
            case 4: w = w5; n = 576; s = is5; break;
            default: w = w6; n = 576; s = is6; break;
        }
        float acc = 0.f;
        for (int i = lane; i < n; i += 64) acc += w[co * n + i];
#pragma unroll
        for (int off = 1; off < 64; off <<= 1) acc += __shfl_xor(acc, off);
        if (lane == 0) s[co] = 1.0f / acc;
        return;
    }
    int idx = blockIdx.x * 256 + tid;
    if (idx < 800) {
        int co = idx / 25, t = idx % 25;
        wt1[t * 32 + co] = w1[idx];
        return;
    }
    if (idx < 992) return;
    int r = idx - 992;
    const float* w; unsigned short* wf; int CIN, KK, cxor;
    if (r < 25600)        {             w = w2; wf = wf2; CIN = 32; KK = 25; cxor = 0;  }
    else if (r < 51200)   { r -= 25600; w = w3; wf = wf3; CIN = 32; KK = 25; cxor = 0;  }
    else if (r < 69632)   { r -= 51200; w = w4; wf = wf4; CIN = 64; KK = 9;  cxor = 0;  }
    else if (r < 88064)   { r -= 69632; w = w5; wf = wf5; CIN = 64; KK = 9;  cxor = 0;  }
    else if (r < 106496)  { r -= 88064; w = w6; wf = wf6; CIN = 64; KK = 9;  cxor = 32; }
    else return;
    int j = r & 7, lane = (r >> 3) & 63, cot = (r >> 9) & 1, ks = r >> 10;
    int phase = ks / KK, tap = ks - phase * KK;
    int co = cot * 16 + (lane & 15);
    int ci = (phase * 32 + (lane >> 4) * 8 + j) ^ cxor;
    wf[r] = f2bf(w[((long)co * CIN + ci) * KK + tap]);
}

// ---------------------------------------------------------------------------
// conv1: CIN=1 direct VALU conv, LDS-staged. Input planar fp32
// [b][{data,conf}][H][W]; output channel-last bf16 [b*2+pc][pix][32ci].
// ---------------------------------------------------------------------------
__global__ __launch_bounds__(256)
void conv1_k(const float* __restrict__ x, const float* __restrict__ wt,
             const float* __restrict__ bias, const float* __restrict__ is_,
             unsigned short* __restrict__ out, int H, int W) {
    constexpr int TIW = 36, TIH = 12, TSZ = TIW * TIH;  // 432
    __shared__ float sc[TSZ], sp[TSZ];
    const int tid = threadIdx.x;
    const int tx = tid & 31, ty = tid >> 5;
    const int ox0 = blockIdx.x * 32, oy0 = blockIdx.y * 8, b = blockIdx.z;
    const long HW = (long)H * W;
    const float* xd = x + (long)(b * 2) * HW;
    const float* xc = xd + HW;

    for (int i = tid; i < TSZ; i += 256) {
        int py = i / TIW, px = i - py * TIW;
        int gy = oy0 - 2 + py, gx = ox0 - 2 + px;
        float c = 0.f, d = 0.f;
        if (gy >= 0 && gy < H && gx >= 0 && gx < W) {
            long g = (long)gy * W + gx;
            c = xc[g]; d = xd[g];
        }
        sc[i] = c;
        sp[i] = d * c;
    }
    __syncthreads();

    float ac[32], ap[32];
#pragma unroll
    for (int i = 0; i < 32; ++i) { ac[i] = 0.f; ap[i] = 0.f; }
#pragma unroll
    for (int dy = 0; dy < 5; ++dy) {
#pragma unroll
        for (int dx = 0; dx < 5; ++dx) {
            const int li = (ty + dy) * TIW + tx + dx;
            float cf = sc[li];
            float pv = sp[li];
            const float* wr = wt + (dy * 5 + dx) * 32;
#pragma unroll
            for (int co = 0; co < 32; ++co) {
                ac[co] = fmaf(wr[co], cf, ac[co]);
                ap[co] = fmaf(wr[co], pv, ap[co]);
            }
        }
    }

    const int xx = ox0 + tx, yy = oy0 + ty;
    unsigned short* po = out + ((long)(b * 2 + 0) * HW + (long)yy * W + xx) * 32;
    unsigned short* co_ = out + ((long)(b * 2 + 1) * HW + (long)yy * W + xx) * 32;
#pragma unroll
    for (int g = 0; g < 4; ++g) {
        uint4 vp, vc;
        unsigned int pw[4], cw[4];
#pragma unroll
        for (int h = 0; h < 4; ++h) {
            int c0 = g * 8 + h * 2, c1 = c0 + 1;
            float d0 = ac[c0], d1 = ac[c1];
            float ox0v = fmaf(ap[c0], frcp(d0 + EPSF), bias[c0]);
            float ox1v = fmaf(ap[c1], frcp(d1 + EPSF), bias[c1]);
            float oc0 = d0 * is_[c0], oc1 = d1 * is_[c1];
            pw[h] = (unsigned int)f2bf(ox0v * oc0) | ((unsigned int)f2bf(ox1v * oc1) << 16);
            cw[h] = (unsigned int)f2bf(oc0) | ((unsigned int)f2bf(oc1) << 16);
        }
        vp.x = pw[0]; vp.y = pw[1]; vp.z = pw[2]; vp.w = pw[3];
        vc.x = cw[0]; vc.y = cw[1]; vc.z = cw[2]; vc.w = cw[3];
        *(uint4*)(po + g * 8) = vp;
        *(uint4*)(co_ + g * 8) = vc;
    }
}

// ---------------------------------------------------------------------------
// MFMA implicit-GEMM nconv (channel-last bf16 [b*2+pc][y][x][32ci]).
// 16x8 output tile, 256 thr = 4 waves; wave wv owns rows {2wv,2wv+1}
// (mt = row), 16 px each. Tap loop: ROW-REUSE (dx-outer / row-inner).
// R16: staging uses __builtin_amdgcn_global_load_lds width=16 (direct
// global->LDS DMA, no VGPR round-trip, no ds_write issue slots). The
// ch = it*256+tid mapping is lane-linear (dest = wave-uniform base +
// lane*16 — the m104/m108 constraint), so the LDS tile layout is LINEAR
// (no staging swizzle); OOB halo lanes fetch from a 16-B zero page.
// Tap reads are linear p*32+q*8 (bank audit: 2 lanes/bank = free, m136).
// Epilogue bounce keeps its own self-consistent swizzled layout.
// Per tap: K=32 ci in one 16x16x32 k-step. D: col=lane&15=pixel,
// row=(lane>>4)*4+reg=co. NPH=2 stages src2 (half-res, up2'd in staging).
// POOL: fused 2x2 stride-2 max-pool. FUSE7 fuses the final 1x1 nconv.
// ---------------------------------------------------------------------------
template <int KS, int NPH, bool FUSE7, bool POOL>
__global__ __launch_bounds__(256, 4)
void mconv_k(const unsigned short* __restrict__ s1,
             const unsigned short* __restrict__ s2,
             const unsigned short* __restrict__ wf,
             const float* __restrict__ bias, const float* __restrict__ sden,
             unsigned short* __restrict__ out, float* __restrict__ xout,
             const float* __restrict__ w7, const float* __restrict__ b7,
             unsigned short* __restrict__ pout,
             const unsigned int* __restrict__ zpage,
             int H, int W) {
    constexpr int R = KS / 2, KK = KS * KS;
    constexpr int TIH = 8 + KS - 1, TIW = 16 + KS - 1;    // 12x20 (KS=5) / 10x18 (KS=3)
    constexpr int PCS = TIH * TIW * 32;        // ushorts per pc-plane
    constexpr int NCH = TIH * TIW * 4;         // 16B chunks per pc-plane
    __shared__ unsigned short lds[2 * PCS];

    const int tid = threadIdx.x;
    const int wv = tid >> 6, lane = tid & 63, n = lane & 15, q = lane >> 4;
    const int ox0 = blockIdx.x * 16, oy0 = blockIdx.y * 8, b = blockIdx.z;
    const long HW = (long)H * W;

    float4f accP[2][2], accC[2][2];
#pragma unroll
    for (int mt = 0; mt < 2; ++mt)
#pragma unroll
        for (int ct = 0; ct < 2; ++ct) {
            accP[mt][ct] = (float4f)0.f;
            accC[mt][ct] = (float4f)0.f;
        }

    const int PB = (2 * wv) * TIW + n;   // lane pixel base (2 rows per wave)

    for (int ph = 0; ph < NPH; ++ph) {
        const unsigned short* src = (NPH == 2 && ph == 1) ? s2 : s1;
        if (ph) __syncthreads();
        // ---- stage tile via global->LDS DMA (linear layout, zero page OOB) ----
        for (int it = 0; it < (2 * NCH + 255) / 256; ++it) {
            int ch = it * 256 + tid;
            if (ch < 2 * NCH) {
                int pc = ch / NCH, c2 = ch - pc * NCH;
                int pix = c2 >> 2, k8 = c2 & 3;
                int py = pix / TIW, px = pix - py * TIW;
                int gy = oy0 - R + py, gx = ox0 - R + px;
                const unsigned short* ga;
                if (gy >= 0 && gy < H && gx >= 0 && gx < W) {
                    long gi;
                    if (NPH == 2 && ph == 1)
                        gi = ((long)(b * 2 + pc) * (HW >> 2) +
                              (long)(gy >> 1) * (W >> 1) + (gx >> 1)) * 32 + k8 * 8;
                    else
                        gi = ((long)(b * 2 + pc) * HW + (long)gy * W + gx) * 32 + k8 * 8;
                    ga = src + gi;
                } else {
                    ga = (const unsigned short*)zpage;
                }
                // wave-uniform LDS base; lane data lands at base + lane*16
                __builtin_amdgcn_global_load_lds(
                    (gas_t)ga,
                    (las_t)(lds + (size_t)(it * 256 + wv * 64) * 8),
                    16, 0, 0);
            }
        }
        __syncthreads();
        // ---- tap loop: dx-outer, row-inner; one B-read serves both mt ----
#pragma unroll
        for (int dx = 0; dx < KS; ++dx) {
            short8 a0p, a1p;   // A-frags of previous row's tap (mt=1 operand)
#pragma unroll
            for (int r = 0; r < KS + 1; ++r) {
                short8 a0c, a1c;
                if (r < KS) {
                    const int ks = ph * KK + r * KS + dx;
                    a0c = ((const short8*)wf)[(ks * 2 + 0) * 64 + lane];
                    a1c = ((const short8*)wf)[(ks * 2 + 1) * 64 + lane];
                }
                const int p = PB + r * TIW + dx;
                const int off = p * 32 + q * 8;
                short8 bp = *(const short8*)(lds + off);
                short8 bc = *(const short8*)(lds + off + PCS);
                if (r < KS) {   // mt=0, dy=r
                    accP[0][0] = __builtin_amdgcn_mfma_f32_16x16x32_bf16(a0c, bp, accP[0][0], 0, 0, 0);
                    accP[0][1] = __builtin_amdgcn_mfma_f32_16x16x32_bf16(a1c, bp, accP[0][1], 0, 0, 0);
                    accC[0][0] = __builtin_amdgcn_mfma_f32_16x16x32_bf16(a0c, bc, accC[0][0], 0, 0, 0);
                    accC[0][1] = __builtin_amdgcn_mfma_f32_16x16x32_bf16(a1c, bc, accC[0][1], 0, 0, 0);
                }
                if (r >= 1) {   // mt=1, dy=r-1 (A of previous row's tap)
                    accP[1][0] = __builtin_amdgcn_mfma_f32_16x16x32_bf16(a0p, bp, accP[1][0], 0, 0, 0);
                    accP[1][1] = __builtin_amdgcn_mfma_f32_16x16x32_bf16(a1p, bp, accP[1][1], 0, 0, 0);
                    accC[1][0] = __builtin_amdgcn_mfma_f32_16x16x32_bf16(a0p, bc, accC[1][0], 0, 0, 0);
                    accC[1][1] = __builtin_amdgcn_mfma_f32_16x16x32_bf16(a1p, bc, accC[1][1], 0, 0, 0);
                }
                a0p = a0c; a1p = a1c;
            }
        }
    }

    // ---- epilogue ----
    float4f b4[2], s4[2];
    b4[0] = *(const float4f*)(bias + q * 4);
    b4[1] = *(const float4f*)(bias + 16 + q * 4);
    s4[0] = *(const float4f*)(sden + q * 4);
    s4[1] = *(const float4f*)(sden + 16 + q * 4);

    if (!FUSE7) {
        // ---- fused 2x2 pool (before the bounce; accs still live) ----
        if (POOL) {
            const int W2 = W >> 1;
            const long HW4 = HW >> 2;
#pragma unroll
            for (int ct = 0; ct < 2; ++ct) {
                unsigned int pw[2], cw[2];
                unsigned short ps[4], cs[4];
#pragma unroll
                for (int r = 0; r < 4; ++r) {
                    float d0 = accC[0][ct][r], d1 = accC[1][ct][r];
                    float c00 = d0 * s4[ct][r];
                    float c10 = d1 * s4[ct][r];
                    float p00 = fmaf(accP[0][ct][r], frcp(d0 + EPSF), b4[ct][r]) * c00;
                    float p10 = fmaf(accP[1][ct][r], frcp(d1 + EPSF), b4[ct][r]) * c10;
                    float c01 = __shfl_xor(c00, 1), c11 = __shfl_xor(c10, 1);
                    float p01 = __shfl_xor(p00, 1), p11 = __shfl_xor(p10, 1);
                    float bc = c00, bp = p00;                 // first-max, row-major
                    if (c01 > bc) { bc = c01; bp = p01; }
                    if (c10 > bc) { bc = c10; bp = p10; }
                    if (c11 > bc) { bc = c11; bp = p11; }
                    ps[r] = f2bf(bp * 0.25f);
                    cs[r] = f2bf(bc * 0.25f);
                }
                if (!(n & 1)) {
                    pw[0] = (unsigned int)ps[0] | ((unsigned int)ps[1] << 16);
                    pw[1] = (unsigned int)ps[2] | ((unsigned int)ps[3] << 16);
                    cw[0] = (unsigned int)cs[0] | ((unsigned int)cs[1] << 16);
                    cw[1] = (unsigned int)cs[2] | ((unsigned int)cs[3] << 16);
                    int gy2 = (oy0 >> 1) + wv, gx2 = (ox0 >> 1) + (n >> 1);
                    long pb = ((long)gy2 * W2 + gx2) * 32 + ct * 16 + q * 4;
                    uint2 vp; vp.x = pw[0]; vp.y = pw[1];
                    uint2 vc; vc.x = cw[0]; vc.y = cw[1];
                    *(uint2*)(pout + (long)(b * 2 + 0) * HW4 * 32 + pb) = vp;
                    *(uint2*)(pout + (long)(b * 2 + 1) * HW4 * 32 + pb) = vc;
                }
            }
        }
        // ---- LDS bounce, one plane at a time (own swizzled layout) ----
#pragma unroll
        for (int pl = 0; pl < 2; ++pl) {
            __syncthreads();
#pragma unroll
            for (int mt = 0; mt < 2; ++mt) {
                const int pix = (2 * wv + mt) * 16 + n;
#pragma unroll
                for (int ct = 0; ct < 2; ++ct) {
                    unsigned int w0, w1;
                    if (pl == 0) {
                        float d0 = accC[mt][ct][0], d1 = accC[mt][ct][1];
                        float d2 = accC[mt][ct][2], d3 = accC[mt][ct][3];
                        float x0 = fmaf(accP[mt][ct][0], frcp(d0 + EPSF), b4[ct][0]) * (d0 * s4[ct][0]);
                        float x1 = fmaf(accP[mt][ct][1], frcp(d1 + EPSF), b4[ct][1]) * (d1 * s4[ct][1]);
                        float x2 = fmaf(accP[mt][ct][2], frcp(d2 + EPSF), b4[ct][2]) * (d2 * s4[ct][2]);
                        float x3 = fmaf(accP[mt][ct][3], frcp(d3 + EPSF), b4[ct][3]) * (d3 * s4[ct][3]);
                        w0 = (unsigned int)f2bf(x0) | ((unsigned int)f2bf(x1) << 16);
                        w1 = (unsigned int)f2bf(x2) | ((unsigned int)f2bf(x3) << 16);
                    } else {
                        float c0 = accC[mt][ct][0] * s4[ct][0], c1 = accC[mt][ct][1] * s4[ct][1];
                        float c2 = accC[mt][ct][2] * s4[ct][2], c3 = accC[mt][ct][3] * s4[ct][3];
                        w0 = (unsigned int)f2bf(c0) | ((unsigned int)f2bf(c1) << 16);
                        w1 = (unsigned int)f2bf(c2) | ((unsigned int)f2bf(c3) << 16);
                    }
                    uint2 v; v.x = w0; v.y = w1;
                    *(uint2*)(lds + pix * 32 +
                              ((ct * 2 + (q >> 1) + n + (n >> 2)) & 3) * 8 + (q & 1) * 4) = v;
                }
            }
            __syncthreads();
            // 128 px * 64B = 8 KB -> 512 uint4 -> 2 iterations of 256 thr
            const unsigned short* obase = out + (long)(b * 2 + pl) * HW * 32;
#pragma unroll
            for (int it = 0; it < 2; ++it) {
                int off = it * 256 + tid;          // 16B units
                int pix = off >> 2, sub = off & 3;
                uint4 v = *(const uint4*)(lds + pix * 32 + ((sub + pix + (pix >> 2)) & 3) * 8);
                int ry = pix >> 4, rx = pix & 15;
                *(uint4*)(obase + ((long)(oy0 + ry) * W + ox0 + rx) * 32 + sub * 8) = v;
            }
        }
    } else {
        float4f w74[2];
        w74[0] = *(const float4f*)(w7 + q * 4);
        w74[1] = *(const float4f*)(w7 + 16 + q * 4);
        const float b7v = b7[0];
#pragma unroll
        for (int mt = 0; mt < 2; ++mt) {
            float num = 0.f, den = 0.f;
#pragma unroll
            for (int ct = 0; ct < 2; ++ct)
#pragma unroll
                for (int r = 0; r < 4; ++r) {
                    float d = accC[mt][ct][r];
                    float oxv = fmaf(accP[mt][ct][r], frcp(d + EPSF), b4[ct][r]);
                    float oc = d * s4[ct][r];
                    num = fmaf(w74[ct][r], oxv * oc, num);
                    den = fmaf(w74[ct][r], oc, den);
                }
            num += __shfl_xor(num, 16); num += __shfl_xor(num, 32);
            den += __shfl_xor(den, 16); den += __shfl_xor(den, 32);
            if (q == 0) {
                const int oy = oy0 + 2 * wv + mt;
                const int ox = ox0 + n;
                xout[(long)b * HW + (long)oy * W + ox] = fmaf(num, frcp(den + EPSF), b7v);
            }
        }
    }
}

// ---------------------------------------------------------------------------
extern "C" void kernel_launch(void* const* d_in, const int* in_sizes, int n_in,
                              void* d_out, int out_size, void* d_ws, size_t ws_size,
                              hipStream_t stream) {
    const float* x  = (const float*)d_in[0];
    const float* w1 = (const float*)d_in[1];
    const float* b1 = (const float*)d_in[2];
    const float* w2 = (const float*)d_in[3];
    const float* b2 = (const float*)d_in[4];
    const float* w3 = (const float*)d_in[5];
    const float* b3 = (const float*)d_in[6];
    const float* w4 = (const float*)d_in[7];
    const float* b4 = (const float*)d_in[8];
    const float* w5 = (const float*)d_in[9];
    const float* b5 = (const float*)d_in[10];
    const float* w6 = (const float*)d_in[11];
    const float* b6 = (const float*)d_in[12];
    const float* w7 = (const float*)d_in[13];
    const float* b7 = (const float*)d_in[14];

    const size_t HW1 = 512 * 512, HW2s = 256 * 256, HW3s = 128 * 128, HW4s = 64 * 64;

    // ---- weight arena (400000 B) ----
    const size_t WARENA = 400000;
    float* fa = (float*)d_ws;
    float *wt1 = fa;                 // 800 f
    float *s1 = wt1 + 800, *s2 = s1 + 32, *s3 = s2 + 32;   // reciprocal sums
    float *s4 = s3 + 32, *s5 = s4 + 32, *s6 = s5 + 32;     // ends at 992 f
    unsigned int* zpage = (unsigned int*)(fa + 992);       // 16 B zeros @3968 (16B-aligned)
    unsigned short* ua = (unsigned short*)((char*)d_ws + 4096);
    unsigned short *wf2 = ua;              // 25600
    unsigned short *wf3 = wf2 + 25600;     // 25600
    unsigned short *wf4 = wf3 + 25600;     // 18432
    unsigned short *wf5 = wf4 + 18432;     // 18432
    unsigned short *wf6 = wf5 + 18432;     // 18432 -> 213 KB < 400000-4096
    unsigned short* buf = (unsigned short*)((char*)d_ws + WARENA);

    // ---- stage buffers: channel-last bf16 [b*2+pc][HW][32] ----
    const size_t E1 = 2 * 2 * HW1 * 32;    // 33.55M ushort = 67.1 MB
    const size_t E2 = 2 * 2 * HW2s * 32, E3 = 2 * 2 * HW3s * 32, E4 = 2 * 2 * HW4s * 32;
    unsigned short* A = buf;
    unsigned short* B = A + E1;
    // lower-res alias inside B (sum = 22M ushorts <= E1)
    unsigned short* P = B;
    unsigned short* Q = P + E2;
    unsigned short* S = Q + E2;
    unsigned short* T = S + E3;
    unsigned short* U = T + E3;
    unsigned short* V = U + E4;

    if (ws_size < WARENA + 2 * E1 * sizeof(unsigned short)) return;  // 134.62 MB

    // ---- weight prep: single launch (frag blocks + 48 wave-sum blocks) ----
    wprep_k<<<468, 256, 0, stream>>>(w1, w2, w3, w4, w5, w6,
                                     wt1, s1, s2, s3, s4, s5, s6,
                                     wf2, wf3, wf4, wf5, wf6, zpage);

    dim3 blkm(256);
    dim3 g1c(16, 64, 2);                               // conv1 (32x8 tiles)
    dim3 g1(32, 64, 2), g2(16, 32, 2), g3(8, 16, 2), g4(4, 8, 2);  // 16x8 tiles

    // ---- encoder ----
    conv1_k<<<g1c, blkm, 0, stream>>>(x, wt1, b1, s1, A, 512, 512);
    mconv_k<5, 1, false, false><<<g1, blkm, 0, stream>>>(A, nullptr, wf2, b2, s2, B, nullptr, nullptr, nullptr, nullptr, zpage, 512, 512);
    mconv_k<5, 1, false, true><<<g1, blkm, 0, stream>>>(B, nullptr, wf3, b3, s3, A, nullptr, nullptr, nullptr, P, zpage, 512, 512);   // x1 in A, pooled -> P

    mconv_k<5, 1, false, false><<<g2, blkm, 0, stream>>>(P, nullptr, wf2, b2, s2, Q, nullptr, nullptr, nullptr, nullptr, zpage, 256, 256);
    mconv_k<5, 1, false, true><<<g2, blkm, 0, stream>>>(Q, nullptr, wf3, b3, s3, P, nullptr, nullptr, nullptr, S, zpage, 256, 256);   // x2 in P, pooled -> S

    mconv_k<5, 1, false, true><<<g3, blkm, 0, stream>>>(S, nullptr, wf2, b2, s2, T, nullptr, nullptr, nullptr, U, zpage, 128, 128);   // x3 in T, pooled -> U

    mconv_k<5, 1, false, false><<<g4, blkm, 0, stream>>>(U, nullptr, wf2, b2, s2, V, nullptr, nullptr, nullptr, nullptr, zpage, 64, 64);  // x4 in V

    // ---- decoder ----
    mconv_k<3, 2, false, false><<<g3, blkm, 0, stream>>>(T, V, wf4, b4, s4, S, nullptr, nullptr, nullptr, nullptr, zpage, 128, 128);  // x34 in S
    mconv_k<3, 2, false, false><<<g2, blkm, 0, stream>>>(P, S, wf5, b5, s5, Q, nullptr, nullptr, nullptr, nullptr, zpage, 256, 256);  // x23 in Q
    mconv_k<3, 2, true, false><<<g1, blkm, 0, stream>>>(A, Q, wf6, b6, s6, nullptr, (float*)d_out, w7, b7, nullptr, zpage, 512, 512);
}

// Round 17
// 325.243 us; speedup vs baseline: 2.3318x; 1.1436x over previous
//
#include <hip/hip_runtime.h>
#include <hip/hip_bf16.h>

#define EPSF 1e-20f

using short8  = __attribute__((ext_vector_type(8))) short;
using float4f = __attribute__((ext_vector_type(4))) float;
typedef const __attribute__((address_space(1))) unsigned int* gas_t;
typedef __attribute__((address_space(3))) unsigned int* las_t;

__device__ __forceinline__ unsigned short f2bf(float f) {
    __hip_bfloat16 h = __float2bfloat16(f);
    return __builtin_bit_cast(unsigned short, h);
}
__device__ __forceinline__ float bf2f(unsigned short u) {
    __hip_bfloat16 h = __builtin_bit_cast(__hip_bfloat16, u);
    return __bfloat162float(h);
}
__device__ __forceinline__ float frcp(float x) { return __builtin_amdgcn_rcpf(x); }

// ---------------------------------------------------------------------------
// Unified weight prep (one launch, 472 blocks):
//  blocks [0,424): linear idx
//    [992,107488)    : MFMA A-fragments for w2..w6 (bf16, lane-exact order)
//    [107488,108512) : conv1 A-fragments wf1 (taps-as-K, K padded 25->32
//                      with ZEROS — the zero columns annihilate whatever the
//                      B-build reads for k>=25)
//  blocks [424,472): one WAVE per (layer,co) reciprocal weight sum
//  block 0 also zeroes the 16-B zero page (OOB target for global_load_lds).
// ---------------------------------------------------------------------------
__global__ void wprep_k(const float* __restrict__ w1, const float* __restrict__ w2,
                        const float* __restrict__ w3, const float* __restrict__ w4,
                        const float* __restrict__ w5, const float* __restrict__ w6,
                        float* __restrict__ is1, float* __restrict__ is2,
                        float* __restrict__ is3, float* __restrict__ is4,
                        float* __restrict__ is5, float* __restrict__ is6,
                        unsigned short* __restrict__ wf2, unsigned short* __restrict__ wf3,
                        unsigned short* __restrict__ wf4, unsigned short* __restrict__ wf5,
                        unsigned short* __restrict__ wf6, unsigned short* __restrict__ wf1,
                        unsigned int* __restrict__ zpage) {
    const int tid = threadIdx.x;
    if (blockIdx.x == 0 && tid < 4) zpage[tid] = 0;   // 16-B zero page
    if (blockIdx.x >= 424) {
        int wid = (blockIdx.x - 424) * 4 + (tid >> 6);
        if (wid >= 192) return;
        int task = wid >> 5, co = wid & 31, lane = tid & 63;
        const float* w; int n; float* s;
        switch (task) {
            case 0: w = w1; n = 25;  s = is1; break;
            case 1: w = w2; n = 800; s = is2; break;
            case 2: w = w3; n = 800; s = is3; break;
            case 3: w = w4; n = 576; s = is4; break;
            case 4: w = w5; n = 576; s = is5; break;
            default: w = w6; n = 576; s = is6; break;
        }
        float acc = 0.f;
        for (int i = lane; i < n; i += 64) acc += w[co * n + i];
#pragma unroll
        for (int off = 1; off < 64; off <<= 1) acc += __shfl_xor(acc, off);
        if (lane == 0) s[co] = 1.0f / acc;
        return;
    }
    int idx = blockIdx.x * 256 + tid;
    if (idx < 992) return;
    int r = idx - 992;
    if (r >= 106496) {                      // conv1 fragments (taps-as-K)
        int r2 = r - 106496;
        if (r2 >= 1024) return;
        int j = r2 & 7, lane = (r2 >> 3) & 63, cot = (r2 >> 9) & 1;
        int co = cot * 16 + (lane & 15);
        int tap = (lane >> 4) * 8 + j;
        wf1[r2] = f2bf(tap < 25 ? w1[co * 25 + tap] : 0.f);
        return;
    }
    const float* w; unsigned short* wf; int CIN, KK, cxor;
    if (r < 25600)        {             w = w2; wf = wf2; CIN = 32; KK = 25; cxor = 0;  }
    else if (r < 51200)   { r -= 25600; w = w3; wf = wf3; CIN = 32; KK = 25; cxor = 0;  }
    else if (r < 69632)   { r -= 51200; w = w4; wf = wf4; CIN = 64; KK = 9;  cxor = 0;  }
    else if (r < 88064)   { r -= 69632; w = w5; wf = wf5; CIN = 64; KK = 9;  cxor = 0;  }
    else                  { r -= 88064; w = w6; wf = wf6; CIN = 64; KK = 9;  cxor = 32; }
    int j = r & 7, lane = (r >> 3) & 63, cot = (r >> 9) & 1, ks = r >> 10;
    int phase = ks / KK, tap = ks - phase * KK;
    int co = cot * 16 + (lane & 15);
    int ci = (phase * 32 + (lane >> 4) * 8 + j) ^ cxor;
    wf[r] = f2bf(w[((long)co * CIN + ci) * KK + tap]);
}

// ---------------------------------------------------------------------------
// conv1 (R17): CIN=1 nconv as ONE MFMA k-step with taps-as-K.
// A = wf1[co][k=tap] (zero-padded 25->32); B built per lane: pixel n's taps
// k=q*8+j via scalar ds_read_u16 from a bf16-staged 20x14 tile (2 extra rows
// so k>=25 reads hit real staged data — annihilated by A's zero columns, no
// NaN risk). Per wave: 2 rows x 16 px, 32 reads + 8 MFMA (was 1600 VALU FMA
// per thread). Epilogue = mconv's coalescing LDS bounce.
// Input planar fp32 [b][{data,conf}][H][W]; output channel-last bf16.
// ---------------------------------------------------------------------------
__global__ __launch_bounds__(256)
void conv1_k(const float* __restrict__ x, const unsigned short* __restrict__ wf1,
             const float* __restrict__ bias, const float* __restrict__ is_,
             unsigned short* __restrict__ out, int H, int W) {
    constexpr int TIW = 20, TIH = 14, TSZ = TIW * TIH;   // 280
    __shared__ unsigned short sp[TSZ], sc_[TSZ];
    __shared__ unsigned short lbb[128 * 32];             // 8 KB bounce
    const int tid = threadIdx.x;
    const int wv = tid >> 6, lane = tid & 63, n = lane & 15, q = lane >> 4;
    const int ox0 = blockIdx.x * 16, oy0 = blockIdx.y * 8, b = blockIdx.z;
    const long HW = (long)H * W;
    const float* xd = x + (long)(b * 2) * HW;
    const float* xc = xd + HW;

    for (int i = tid; i < TSZ; i += 256) {
        int py = i / TIW, px = i - py * TIW;
        int gy = oy0 - 2 + py, gx = ox0 - 2 + px;
        float c = 0.f, d = 0.f;
        if (gy >= 0 && gy < H && gx >= 0 && gx < W) {
            long g = (long)gy * W + gx;
            c = xc[g]; d = xd[g];
        }
        sc_[i] = f2bf(c);
        sp[i] = f2bf(d * c);
    }
    __syncthreads();

    int loff[8];                      // per-lane tap offsets (k = q*8+j)
#pragma unroll
    for (int j = 0; j < 8; ++j) {
        int k = q * 8 + j;
        int dy = k / 5, dx = k - 5 * dy;
        loff[j] = dy * TIW + dx;
    }
    short8 a0 = ((const short8*)wf1)[0 * 64 + lane];
    short8 a1 = ((const short8*)wf1)[1 * 64 + lane];

    float4f accP[2][2], accC[2][2];
#pragma unroll
    for (int mt = 0; mt < 2; ++mt) {
        const int rb = (2 * wv + mt) * TIW + n;
        union { short8 v; unsigned short s[8]; } bp, bc;
#pragma unroll
        for (int j = 0; j < 8; ++j) {
            bp.s[j] = sp[rb + loff[j]];
            bc.s[j] = sc_[rb + loff[j]];
        }
        accP[mt][0] = __builtin_amdgcn_mfma_f32_16x16x32_bf16(a0, bp.v, (float4f)0.f, 0, 0, 0);
        accP[mt][1] = __builtin_amdgcn_mfma_f32_16x16x32_bf16(a1, bp.v, (float4f)0.f, 0, 0, 0);
        accC[mt][0] = __builtin_amdgcn_mfma_f32_16x16x32_bf16(a0, bc.v, (float4f)0.f, 0, 0, 0);
        accC[mt][1] = __builtin_amdgcn_mfma_f32_16x16x32_bf16(a1, bc.v, (float4f)0.f, 0, 0, 0);
    }

    float4f b4[2], s4[2];
    b4[0] = *(const float4f*)(bias + q * 4);
    b4[1] = *(const float4f*)(bias + 16 + q * 4);
    s4[0] = *(const float4f*)(is_ + q * 4);
    s4[1] = *(const float4f*)(is_ + 16 + q * 4);

#pragma unroll
    for (int pl = 0; pl < 2; ++pl) {
        __syncthreads();
#pragma unroll
        for (int mt = 0; mt < 2; ++mt) {
            const int pix = (2 * wv + mt) * 16 + n;
#pragma unroll
            for (int ct = 0; ct < 2; ++ct) {
                unsigned int w0, w1v;
                if (pl == 0) {
                    float d0 = accC[mt][ct][0], d1 = accC[mt][ct][1];
                    float d2 = accC[mt][ct][2], d3 = accC[mt][ct][3];
                    float x0 = fmaf(accP[mt][ct][0], frcp(d0 + EPSF), b4[ct][0]) * (d0 * s4[ct][0]);
                    float x1 = fmaf(accP[mt][ct][1], frcp(d1 + EPSF), b4[ct][1]) * (d1 * s4[ct][1]);
                    float x2 = fmaf(accP[mt][ct][2], frcp(d2 + EPSF), b4[ct][2]) * (d2 * s4[ct][2]);
                    float x3 = fmaf(accP[mt][ct][3], frcp(d3 + EPSF), b4[ct][3]) * (d3 * s4[ct][3]);
                    w0 = (unsigned int)f2bf(x0) | ((unsigned int)f2bf(x1) << 16);
                    w1v = (unsigned int)f2bf(x2) | ((unsigned int)f2bf(x3) << 16);
                } else {
                    float c0 = accC[mt][ct][0] * s4[ct][0], c1 = accC[mt][ct][1] * s4[ct][1];
                    float c2 = accC[mt][ct][2] * s4[ct][2], c3 = accC[mt][ct][3] * s4[ct][3];
                    w0 = (unsigned int)f2bf(c0) | ((unsigned int)f2bf(c1) << 16);
                    w1v = (unsigned int)f2bf(c2) | ((unsigned int)f2bf(c3) << 16);
                }
                uint2 v; v.x = w0; v.y = w1v;
                *(uint2*)(lbb + pix * 32 +
                          ((ct * 2 + (q >> 1) + n + (n >> 2)) & 3) * 8 + (q & 1) * 4) = v;
            }
        }
        __syncthreads();
        const unsigned short* obase = out + (long)(b * 2 + pl) * HW * 32;
#pragma unroll
        for (int it = 0; it < 2; ++it) {
            int off = it * 256 + tid;          // 16B units
            int pix = off >> 2, sub = off & 3;
            uint4 v = *(const uint4*)(lbb + pix * 32 + ((sub + pix + (pix >> 2)) & 3) * 8);
            int ry = pix >> 4, rx = pix & 15;
            *(uint4*)(obase + ((long)(oy0 + ry) * W + ox0 + rx) * 32 + sub * 8) = v;
        }
    }
}

// ---------------------------------------------------------------------------
// MFMA implicit-GEMM nconv (channel-last bf16 [b*2+pc][y][x][32ci]).
// 16x8 output tile, 256 thr = 4 waves; wave wv owns rows {2wv,2wv+1}
// (mt = row), 16 px each. Tap loop: ROW-REUSE (dx-outer / row-inner).
// Staging via __builtin_amdgcn_global_load_lds width=16 (direct DMA, linear
// LDS layout, lane-linear mapping, 16-B zero page for OOB halo lanes).
// Per tap: K=32 ci in one 16x16x32 k-step. D: col=lane&15=pixel,
// row=(lane>>4)*4+reg=co. NPH=2 stages src2 (half-res, up2'd in staging).
// POOL: fused 2x2 stride-2 max-pool. FUSE7 fuses the final 1x1 nconv.
// Epilogue bounces through LDS for full-line uint4 global writes.
// ---------------------------------------------------------------------------
template <int KS, int NPH, bool FUSE7, bool POOL>
__global__ __launch_bounds__(256, 4)
void mconv_k(const unsigned short* __restrict__ s1,
             const unsigned short* __restrict__ s2,
             const unsigned short* __restrict__ wf,
             const float* __restrict__ bias, const float* __restrict__ sden,
             unsigned short* __restrict__ out, float* __restrict__ xout,
             const float* __restrict__ w7, const float* __restrict__ b7,
             unsigned short* __restrict__ pout,
             const unsigned int* __restrict__ zpage,
             int H, int W) {
    constexpr int R = KS / 2, KK = KS * KS;
    constexpr int TIH = 8 + KS - 1, TIW = 16 + KS - 1;    // 12x20 (KS=5) / 10x18 (KS=3)
    constexpr int PCS = TIH * TIW * 32;        // ushorts per pc-plane
    constexpr int NCH = TIH * TIW * 4;         // 16B chunks per pc-plane
    __shared__ unsigned short lds[2 * PCS];

    const int tid = threadIdx.x;
    const int wv = tid >> 6, lane = tid & 63, n = lane & 15, q = lane >> 4;
    const int ox0 = blockIdx.x * 16, oy0 = blockIdx.y * 8, b = blockIdx.z;
    const long HW = (long)H * W;

    float4f accP[2][2], accC[2][2];
#pragma unroll
    for (int mt = 0; mt < 2; ++mt)
#pragma unroll
        for (int ct = 0; ct < 2; ++ct) {
            accP[mt][ct] = (float4f)0.f;
            accC[mt][ct] = (float4f)0.f;
        }

    const int PB = (2 * wv) * TIW + n;   // lane pixel base (2 rows per wave)

    for (int ph = 0; ph < NPH; ++ph) {
        const unsigned short* src = (NPH == 2 && ph == 1) ? s2 : s1;
        if (ph) __syncthreads();
        // ---- stage tile via global->LDS DMA (linear layout, zero page OOB) ----
        for (int it = 0; it < (2 * NCH + 255) / 256; ++it) {
            int ch = it * 256 + tid;
            if (ch < 2 * NCH) {
                int pc = ch / NCH, c2 = ch - pc * NCH;
                int pix = c2 >> 2, k8 = c2 & 3;
                int py = pix / TIW, px = pix - py * TIW;
                int gy = oy0 - R + py, gx = ox0 - R + px;
                const unsigned short* ga;
                if (gy >= 0 && gy < H && gx >= 0 && gx < W) {
                    long gi;
                    if (NPH == 2 && ph == 1)
                        gi = ((long)(b * 2 + pc) * (HW >> 2) +
                              (long)(gy >> 1) * (W >> 1) + (gx >> 1)) * 32 + k8 * 8;
                    else
                        gi = ((long)(b * 2 + pc) * HW + (long)gy * W + gx) * 32 + k8 * 8;
                    ga = src + gi;
                } else {
                    ga = (const unsigned short*)zpage;
                }
                __builtin_amdgcn_global_load_lds(
                    (gas_t)ga,
                    (las_t)(lds + (size_t)(it * 256 + wv * 64) * 8),
                    16, 0, 0);
            }
        }
        __syncthreads();
        // ---- tap loop: dx-outer, row-inner; one B-read serves both mt ----
#pragma unroll
        for (int dx = 0; dx < KS; ++dx) {
            short8 a0p, a1p;   // A-frags of previous row's tap (mt=1 operand)
#pragma unroll
            for (int r = 0; r < KS + 1; ++r) {
                short8 a0c, a1c;
                if (r < KS) {
                    const int ks = ph * KK + r * KS + dx;
                    a0c = ((const short8*)wf)[(ks * 2 + 0) * 64 + lane];
                    a1c = ((const short8*)wf)[(ks * 2 + 1) * 64 + lane];
                }
                const int p = PB + r * TIW + dx;
                const int off = p * 32 + q * 8;
                short8 bp = *(const short8*)(lds + off);
                short8 bc = *(const short8*)(lds + off + PCS);
                if (r < KS) {   // mt=0, dy=r
                    accP[0][0] = __builtin_amdgcn_mfma_f32_16x16x32_bf16(a0c, bp, accP[0][0], 0, 0, 0);
                    accP[0][1] = __builtin_amdgcn_mfma_f32_16x16x32_bf16(a1c, bp, accP[0][1], 0, 0, 0);
                    accC[0][0] = __builtin_amdgcn_mfma_f32_16x16x32_bf16(a0c, bc, accC[0][0], 0, 0, 0);
                    accC[0][1] = __builtin_amdgcn_mfma_f32_16x16x32_bf16(a1c, bc, accC[0][1], 0, 0, 0);
                }
                if (r >= 1) {   // mt=1, dy=r-1 (A of previous row's tap)
                    accP[1][0] = __builtin_amdgcn_mfma_f32_16x16x32_bf16(a0p, bp, accP[1][0], 0, 0, 0);
                    accP[1][1] = __builtin_amdgcn_mfma_f32_16x16x32_bf16(a1p, bp, accP[1][1], 0, 0, 0);
                    accC[1][0] = __builtin_amdgcn_mfma_f32_16x16x32_bf16(a0p, bc, accC[1][0], 0, 0, 0);
                    accC[1][1] = __builtin_amdgcn_mfma_f32_16x16x32_bf16(a1p, bc, accC[1][1], 0, 0, 0);
                }
                a0p = a0c; a1p = a1c;
            }
        }
    }

    // ---- epilogue ----
    float4f b4[2], s4[2];
    b4[0] = *(const float4f*)(bias + q * 4);
    b4[1] = *(const float4f*)(bias + 16 + q * 4);
    s4[0] = *(const float4f*)(sden + q * 4);
    s4[1] = *(const float4f*)(sden + 16 + q * 4);

    if (!FUSE7) {
        // ---- fused 2x2 pool (before the bounce; accs still live) ----
        if (POOL) {
            const int W2 = W >> 1;
            const long HW4 = HW >> 2;
#pragma unroll
            for (int ct = 0; ct < 2; ++ct) {
                unsigned int pw[2], cw[2];
                unsigned short ps[4], cs[4];
#pragma unroll
                for (int r = 0; r < 4; ++r) {
                    float d0 = accC[0][ct][r], d1 = accC[1][ct][r];
                    float c00 = d0 * s4[ct][r];
                    float c10 = d1 * s4[ct][r];
                    float p00 = fmaf(accP[0][ct][r], frcp(d0 + EPSF), b4[ct][r]) * c00;
                    float p10 = fmaf(accP[1][ct][r], frcp(d1 + EPSF), b4[ct][r]) * c10;
                    float c01 = __shfl_xor(c00, 1), c11 = __shfl_xor(c10, 1);
                    float p01 = __shfl_xor(p00, 1), p11 = __shfl_xor(p10, 1);
                    float bc = c00, bp = p00;                 // first-max, row-major
                    if (c01 > bc) { bc = c01; bp = p01; }
                    if (c10 > bc) { bc = c10; bp = p10; }
                    if (c11 > bc) { bc = c11; bp = p11; }
                    ps[r] = f2bf(bp * 0.25f);
                    cs[r] = f2bf(bc * 0.25f);
                }
                if (!(n & 1)) {
                    pw[0] = (unsigned int)ps[0] | ((unsigned int)ps[1] << 16);
                    pw[1] = (unsigned int)ps[2] | ((unsigned int)ps[3] << 16);
                    cw[0] = (unsigned int)cs[0] | ((unsigned int)cs[1] << 16);
                    cw[1] = (unsigned int)cs[2] | ((unsigned int)cs[3] << 16);
                    int gy2 = (oy0 >> 1) + wv, gx2 = (ox0 >> 1) + (n >> 1);
                    long pb = ((long)gy2 * W2 + gx2) * 32 + ct * 16 + q * 4;
                    uint2 vp; vp.x = pw[0]; vp.y = pw[1];
                    uint2 vc; vc.x = cw[0]; vc.y = cw[1];
                    *(uint2*)(pout + (long)(b * 2 + 0) * HW4 * 32 + pb) = vp;
                    *(uint2*)(pout + (long)(b * 2 + 1) * HW4 * 32 + pb) = vc;
                }
            }
        }
        // ---- LDS bounce, one plane at a time (own swizzled layout) ----
#pragma unroll
        for (int pl = 0; pl < 2; ++pl) {
            __syncthreads();
#pragma unroll
            for (int mt = 0; mt < 2; ++mt) {
                const int pix = (2 * wv + mt) * 16 + n;
#pragma unroll
                for (int ct = 0; ct < 2; ++ct) {
                    unsigned int w0, w1;
                    if (pl == 0) {
                        float d0 = accC[mt][ct][0], d1 = accC[mt][ct][1];
                        float d2 = accC[mt][ct][2], d3 = accC[mt][ct][3];
                        float x0 = fmaf(accP[mt][ct][0], frcp(d0 + EPSF), b4[ct][0]) * (d0 * s4[ct][0]);
                        float x1 = fmaf(accP[mt][ct][1], frcp(d1 + EPSF), b4[ct][1]) * (d1 * s4[ct][1]);
                        float x2 = fmaf(accP[mt][ct][2], frcp(d2 + EPSF), b4[ct][2]) * (d2 * s4[ct][2]);
                        float x3 = fmaf(accP[mt][ct][3], frcp(d3 + EPSF), b4[ct][3]) * (d3 * s4[ct][3]);
                        w0 = (unsigned int)f2bf(x0) | ((unsigned int)f2bf(x1) << 16);
                        w1 = (unsigned int)f2bf(x2) | ((unsigned int)f2bf(x3) << 16);
                    } else {
                        float c0 = accC[mt][ct][0] * s4[ct][0], c1 = accC[mt][ct][1] * s4[ct][1];
                        float c2 = accC[mt][ct][2] * s4[ct][2], c3 = accC[mt][ct][3] * s4[ct][3];
                        w0 = (unsigned int)f2bf(c0) | ((unsigned int)f2bf(c1) << 16);
                        w1 = (unsigned int)f2bf(c2) | ((unsigned int)f2bf(c3) << 16);
                    }
                    uint2 v; v.x = w0; v.y = w1;
                    *(uint2*)(lds + pix * 32 +
                              ((ct * 2 + (q >> 1) + n + (n >> 2)) & 3) * 8 + (q & 1) * 4) = v;
                }
            }
            __syncthreads();
            // 128 px * 64B = 8 KB -> 512 uint4 -> 2 iterations of 256 thr
            const unsigned short* obase = out + (long)(b * 2 + pl) * HW * 32;
#pragma unroll
            for (int it = 0; it < 2; ++it) {
                int off = it * 256 + tid;          // 16B units
                int pix = off >> 2, sub = off & 3;
                uint4 v = *(const uint4*)(lds + pix * 32 + ((sub + pix + (pix >> 2)) & 3) * 8);
                int ry = pix >> 4, rx = pix & 15;
                *(uint4*)(obase + ((long)(oy0 + ry) * W + ox0 + rx) * 32 + sub * 8) = v;
            }
        }
    } else {
        float4f w74[2];
        w74[0] = *(const float4f*)(w7 + q * 4);
        w74[1] = *(const float4f*)(w7 + 16 + q * 4);
        const float b7v = b7[0];
#pragma unroll
        for (int mt = 0; mt < 2; ++mt) {
            float num = 0.f, den = 0.f;
#pragma unroll
            for (int ct = 0; ct < 2; ++ct)
#pragma unroll
                for (int r = 0; r < 4; ++r) {
                    float d = accC[mt][ct][r];
                    float oxv = fmaf(accP[mt][ct][r], frcp(d + EPSF), b4[ct][r]);
                    float oc = d * s4[ct][r];
                    num = fmaf(w74[ct][r], oxv * oc, num);
                    den = fmaf(w74[ct][r], oc, den);
                }
            num += __shfl_xor(num, 16); num += __shfl_xor(num, 32);
            den += __shfl_xor(den, 16); den += __shfl_xor(den, 32);
            if (q == 0) {
                const int oy = oy0 + 2 * wv + mt;
                const int ox = ox0 + n;
                xout[(long)b * HW + (long)oy * W + ox] = fmaf(num, frcp(den + EPSF), b7v);
            }
        }
    }
}

// ---------------------------------------------------------------------------
extern "C" void kernel_launch(void* const* d_in, const int* in_sizes, int n_in,
                              void* d_out, int out_size, void* d_ws, size_t ws_size,
                              hipStream_t stream) {
    const float* x  = (const float*)d_in[0];
    const float* w1 = (const float*)d_in[1];
    const float* b1 = (const float*)d_in[2];
    const float* w2 = (const float*)d_in[3];
    const float* b2 = (const float*)d_in[4];
    const float* w3 = (const float*)d_in[5];
    const float* b3 = (const float*)d_in[6];
    const float* w4 = (const float*)d_in[7];
    const float* b4 = (const float*)d_in[8];
    const float* w5 = (const float*)d_in[9];
    const float* b5 = (const float*)d_in[10];
    const float* w6 = (const float*)d_in[11];
    const float* b6 = (const float*)d_in[12];
    const float* w7 = (const float*)d_in[13];
    const float* b7 = (const float*)d_in[14];

    const size_t HW1 = 512 * 512, HW2s = 256 * 256, HW3s = 128 * 128, HW4s = 64 * 64;

    // ---- weight arena (400000 B) ----
    const size_t WARENA = 400000;
    float* fa = (float*)d_ws;
    float *s1 = fa, *s2 = s1 + 32, *s3 = s2 + 32;          // reciprocal sums
    float *s4 = s3 + 32, *s5 = s4 + 32, *s6 = s5 + 32;     // ends at 192 f
    unsigned int* zpage = (unsigned int*)(fa + 192);       // 16 B zeros (16B-aligned)
    unsigned short* ua = (unsigned short*)((char*)d_ws + 4096);
    unsigned short *wf2 = ua;              // 25600
    unsigned short *wf3 = wf2 + 25600;     // 25600
    unsigned short *wf4 = wf3 + 25600;     // 18432
    unsigned short *wf5 = wf4 + 18432;     // 18432
    unsigned short *wf6 = wf5 + 18432;     // 18432
    unsigned short *wf1 = wf6 + 18432;     // 1024 -> 215 KB < 400000-4096
    unsigned short* buf = (unsigned short*)((char*)d_ws + WARENA);

    // ---- stage buffers: channel-last bf16 [b*2+pc][HW][32] ----
    const size_t E1 = 2 * 2 * HW1 * 32;    // 33.55M ushort = 67.1 MB
    const size_t E2 = 2 * 2 * HW2s * 32, E3 = 2 * 2 * HW3s * 32, E4 = 2 * 2 * HW4s * 32;
    unsigned short* A = buf;
    unsigned short* B = A + E1;
    // lower-res alias inside B (sum = 22M ushorts <= E1)
    unsigned short* P = B;
    unsigned short* Q = P + E2;
    unsigned short* S = Q + E2;
    unsigned short* T = S + E3;
    unsigned short* U = T + E3;
    unsigned short* V = U + E4;

    if (ws_size < WARENA + 2 * E1 * sizeof(unsigned short)) return;  // 134.62 MB

    // ---- weight prep: single launch (frag blocks + 48 wave-sum blocks) ----
    wprep_k<<<472, 256, 0, stream>>>(w1, w2, w3, w4, w5, w6,
                                     s1, s2, s3, s4, s5, s6,
                                     wf2, wf3, wf4, wf5, wf6, wf1, zpage);

    dim3 blkm(256);
    dim3 g1(32, 64, 2), g2(16, 32, 2), g3(8, 16, 2), g4(4, 8, 2);  // 16x8 tiles

    // ---- encoder ----
    conv1_k<<<g1, blkm, 0, stream>>>(x, wf1, b1, s1, A, 512, 512);
    mconv_k<5, 1, false, false><<<g1, blkm, 0, stream>>>(A, nullptr, wf2, b2, s2, B, nullptr, nullptr, nullptr, nullptr, zpage, 512, 512);
    mconv_k<5, 1, false, true><<<g1, blkm, 0, stream>>>(B, nullptr, wf3, b3, s3, A, nullptr, nullptr, nullptr, P, zpage, 512, 512);   // x1 in A, pooled -> P

    mconv_k<5, 1, false, false><<<g2, blkm, 0, stream>>>(P, nullptr, wf2, b2, s2, Q, nullptr, nullptr, nullptr, nullptr, zpage, 256, 256);
    mconv_k<5, 1, false, true><<<g2, blkm, 0, stream>>>(Q, nullptr, wf3, b3, s3, P, nullptr, nullptr, nullptr, S, zpage, 256, 256);   // x2 in P, pooled -> S

    mconv_k<5, 1, false, true><<<g3, blkm, 0, stream>>>(S, nullptr, wf2, b2, s2, T, nullptr, nullptr, nullptr, U, zpage, 128, 128);   // x3 in T, pooled -> U

    mconv_k<5, 1, false, false><<<g4, blkm, 0, stream>>>(U, nullptr, wf2, b2, s2, V, nullptr, nullptr, nullptr, nullptr, zpage, 64, 64);  // x4 in V

    // ---- decoder ----
    mconv_k<3, 2, false, false><<<g3, blkm, 0, stream>>>(T, V, wf4, b4, s4, S, nullptr, nullptr, nullptr, nullptr, zpage, 128, 128);  // x34 in S
    mconv_k<3, 2, false, false><<<g2, blkm, 0, stream>>>(P, S, wf5, b5, s5, Q, nullptr, nullptr, nullptr, nullptr, zpage, 256, 256);  // x23 in Q
    mconv_k<3, 2, true, false><<<g1, blkm, 0, stream>>>(A, Q, wf6, b6, s6, nullptr, (float*)d_out, w7, b7, nullptr, zpage, 512, 512);
}